// Round 1
// baseline (11474.467 us; speedup 1.0000x reference)
//
#include <hip/hip_runtime.h>
#include <hip/hip_bf16.h>

// ---- model constants ----
#define DIMQ 768
#define D_IN 1024
#define NQ 384
#define NBK 12
#define BATCH 2
#define LSEQ 1024
#define DI 1536
#define DS 16
#define DTR 48
#define NH 16
#define HD 48

typedef __attribute__((ext_vector_type(8))) short short8;
typedef __attribute__((ext_vector_type(4))) float f32x4;

#define GF_BIAS 1
#define GF_SOFTPLUS 2
#define GF_ADDT 4
#define GF_ACCUM 8

__device__ __forceinline__ unsigned short f2bf(float f) {
    unsigned int u = __builtin_bit_cast(unsigned int, f);
    u = (u + 0x7FFFu + ((u >> 16) & 1u)) >> 16;
    return (unsigned short)u;
}
__device__ __forceinline__ float bf2f(unsigned short h) {
    unsigned int u = ((unsigned int)h) << 16;
    return __builtin_bit_cast(float, u);
}

// ---------------------------------------------------------------------------
// GEMM: C[M,N] = A[M,K] * B[N,K]^T  (+bias/softplus/add), split-bf16 (3 MFMA)
// 128x128 tile, 4 waves, 16x16x32 bf16 MFMA. grid.z = batched groups.
// ---------------------------------------------------------------------------
__global__ void gemm_kernel(const float* __restrict__ Ag, const float* __restrict__ Bg,
                            float* __restrict__ Cg, const float* __restrict__ biasg,
                            const float* __restrict__ addT,
                            int M, int N, int K, int lda, int ldb, int ldc,
                            long long sA, long long sB, long long sC, long long sBias,
                            int flags)
{
    __shared__ __align__(16) unsigned short As[2][128][40];   // [hi/lo][row][k] +pad
    __shared__ __align__(16) unsigned short Bs[2][128][40];

    const int z = blockIdx.z;
    const float* A = Ag + (size_t)z * sA;
    const float* B = Bg + (size_t)z * sB;
    float* C = Cg + (size_t)z * sC;

    const int mBase = blockIdx.x * 128;
    const int nBase = blockIdx.y * 128;
    const int tid  = threadIdx.x;
    const int row2 = tid >> 1;       // 0..127
    const int half = tid & 1;        // which 16-wide k half
    const int lane = tid & 63;
    const int wave = tid >> 6;
    const int wm = (wave & 1) * 64;
    const int wn = (wave >> 1) * 64;
    const int lm = lane & 15;
    const int lq = lane >> 4;

    f32x4 acc[4][4] = {};

    const int ktiles = (K + 31) >> 5;
    for (int t = 0; t < ktiles; ++t) {
        const int kb = t * 32 + half * 16;
        // ---- stage A (128x32 f32 -> bf16 hi/lo) ----
        {
            const int gr = mBase + row2;
            const bool rowok = gr < M;
            const float* src = A + (size_t)gr * lda;
            float v[16];
#pragma unroll
            for (int q = 0; q < 4; ++q) {
                const int col = kb + q * 4;
                float4 t4 = make_float4(0.f, 0.f, 0.f, 0.f);
                if (rowok && col < K) t4 = *(const float4*)(src + col);
                v[q*4+0]=t4.x; v[q*4+1]=t4.y; v[q*4+2]=t4.z; v[q*4+3]=t4.w;
            }
            unsigned short hh[16], ll[16];
#pragma unroll
            for (int i = 0; i < 16; ++i) {
                hh[i] = f2bf(v[i]);
                ll[i] = f2bf(v[i] - bf2f(hh[i]));
            }
            unsigned short* dh = &As[0][row2][half*16];
            unsigned short* dl = &As[1][row2][half*16];
#pragma unroll
            for (int c = 0; c < 2; ++c) {
                short8 ph, pl;
#pragma unroll
                for (int j = 0; j < 8; ++j) { ph[j] = (short)hh[c*8+j]; pl[j] = (short)ll[c*8+j]; }
                *(short8*)(dh + c*8) = ph;
                *(short8*)(dl + c*8) = pl;
            }
        }
        // ---- stage B (128x32) ----
        {
            const int gr = nBase + row2;
            const bool rowok = gr < N;
            const float* src = B + (size_t)gr * ldb;
            float v[16];
#pragma unroll
            for (int q = 0; q < 4; ++q) {
                const int col = kb + q * 4;
                float4 t4 = make_float4(0.f, 0.f, 0.f, 0.f);
                if (rowok && col < K) t4 = *(const float4*)(src + col);
                v[q*4+0]=t4.x; v[q*4+1]=t4.y; v[q*4+2]=t4.z; v[q*4+3]=t4.w;
            }
            unsigned short hh[16], ll[16];
#pragma unroll
            for (int i = 0; i < 16; ++i) {
                hh[i] = f2bf(v[i]);
                ll[i] = f2bf(v[i] - bf2f(hh[i]));
            }
            unsigned short* dh = &Bs[0][row2][half*16];
            unsigned short* dl = &Bs[1][row2][half*16];
#pragma unroll
            for (int c = 0; c < 2; ++c) {
                short8 ph, pl;
#pragma unroll
                for (int j = 0; j < 8; ++j) { ph[j] = (short)hh[c*8+j]; pl[j] = (short)ll[c*8+j]; }
                *(short8*)(dh + c*8) = ph;
                *(short8*)(dl + c*8) = pl;
            }
        }
        __syncthreads();
        // ---- compute ----
        short8 ah[4], al[4], bh[4], bl[4];
#pragma unroll
        for (int i = 0; i < 4; ++i) {
            ah[i] = *(const short8*)&As[0][wm + i*16 + lm][lq*8];
            al[i] = *(const short8*)&As[1][wm + i*16 + lm][lq*8];
            bh[i] = *(const short8*)&Bs[0][wn + i*16 + lm][lq*8];
            bl[i] = *(const short8*)&Bs[1][wn + i*16 + lm][lq*8];
        }
#pragma unroll
        for (int i = 0; i < 4; ++i)
#pragma unroll
            for (int j = 0; j < 4; ++j) {
                acc[i][j] = __builtin_amdgcn_mfma_f32_16x16x32_bf16(ah[i], bh[j], acc[i][j], 0, 0, 0);
                acc[i][j] = __builtin_amdgcn_mfma_f32_16x16x32_bf16(ah[i], bl[j], acc[i][j], 0, 0, 0);
                acc[i][j] = __builtin_amdgcn_mfma_f32_16x16x32_bf16(al[i], bh[j], acc[i][j], 0, 0, 0);
            }
        __syncthreads();
    }

    // ---- epilogue: C/D layout col=lane&15, row=(lane>>4)*4+r ----
#pragma unroll
    for (int i = 0; i < 4; ++i)
#pragma unroll
        for (int j = 0; j < 4; ++j)
#pragma unroll
            for (int r = 0; r < 4; ++r) {
                const int m = mBase + wm + i*16 + lq*4 + r;
                const int n = nBase + wn + j*16 + lm;
                if (m < M && n < N) {
                    float v = acc[i][j][r];
                    if (flags & GF_BIAS)     v += biasg[(size_t)z * sBias + n];
                    if (flags & GF_SOFTPLUS) v = (v > 20.f) ? v : log1pf(expf(v));
                    if (flags & GF_ADDT)     v += addT[(size_t)m * ldc + n];
                    if (flags & GF_ACCUM)    v += C[(size_t)m * ldc + n];
                    C[(size_t)m * ldc + n] = v;
                }
            }
}

// ---------------------------------------------------------------------------
// LayerNorm over last dim 768. One wave per row.
// ---------------------------------------------------------------------------
__global__ void ln_kernel(const float* __restrict__ in, float* __restrict__ out,
                          const float* __restrict__ g, const float* __restrict__ b, int rows)
{
    const int row = blockIdx.x * 4 + (threadIdx.x >> 6);
    const int lane = threadIdx.x & 63;
    if (row >= rows) return;
    const float* p = in + (size_t)row * DIMQ;
    float v[12], s = 0.f, s2 = 0.f;
#pragma unroll
    for (int j = 0; j < 12; ++j) {
        v[j] = p[j*64 + lane];
        s += v[j];
        s2 += v[j]*v[j];
    }
#pragma unroll
    for (int o = 32; o; o >>= 1) { s += __shfl_xor(s, o); s2 += __shfl_xor(s2, o); }
    const float mean = s * (1.f/768.f);
    const float var  = s2 * (1.f/768.f) - mean*mean;
    const float inv  = rsqrtf(var + 1e-5f);
    float* q = out + (size_t)row * DIMQ;
#pragma unroll
    for (int j = 0; j < 12; ++j) {
        const int c = j*64 + lane;
        q[c] = (v[j] - mean) * inv * g[c] + b[c];
    }
}

// ---------------------------------------------------------------------------
// Depthwise causal conv1d (DC=4) + silu.  xi = xz[:, :DI] (row stride 3072).
// instShift: inst = batch >> instShift (encoder: 1, blocks: pass offset ptrs + 8)
// ---------------------------------------------------------------------------
__global__ void conv_kernel(const float* __restrict__ xz, float* __restrict__ xc,
                            const float* __restrict__ cw, const float* __restrict__ cb,
                            int Bn, int L, int instShift)
{
    const int idx = blockIdx.x * 256 + threadIdx.x;
    const int total = Bn * L * (DI/4);
    if (idx >= total) return;
    const int d4 = idx % (DI/4);
    const int t  = (idx / (DI/4)) % L;
    const int b  = idx / (L * (DI/4));
    const int inst = b >> instShift;
    const int d = d4 * 4;
    const float* base = xz + (size_t)(b * L) * 3072 + d;
    const float4 w0 = *(const float4*)(cw + (size_t)(inst*DI + d + 0) * 4);
    const float4 w1 = *(const float4*)(cw + (size_t)(inst*DI + d + 1) * 4);
    const float4 w2 = *(const float4*)(cw + (size_t)(inst*DI + d + 2) * 4);
    const float4 w3 = *(const float4*)(cw + (size_t)(inst*DI + d + 3) * 4);
    float4 acc = *(const float4*)(cb + (size_t)inst*DI + d);
    float4 xv[4];
#pragma unroll
    for (int j = 0; j < 4; ++j) {
        const int tt = t - 3 + j;
        xv[j] = (tt >= 0) ? *(const float4*)(base + (size_t)tt * 3072) : make_float4(0,0,0,0);
    }
    acc.x += xv[0].x*w0.x + xv[1].x*w0.y + xv[2].x*w0.z + xv[3].x*w0.w;
    acc.y += xv[0].y*w1.x + xv[1].y*w1.y + xv[2].y*w1.z + xv[3].y*w1.w;
    acc.z += xv[0].z*w2.x + xv[1].z*w2.y + xv[2].z*w2.z + xv[3].z*w2.w;
    acc.w += xv[0].w*w3.x + xv[1].w*w3.y + xv[2].w*w3.z + xv[3].w*w3.w;
    float4 o;
    o.x = acc.x / (1.f + expf(-acc.x));
    o.y = acc.y / (1.f + expf(-acc.y));
    o.z = acc.z / (1.f + expf(-acc.z));
    o.w = acc.w / (1.f + expf(-acc.w));
    *(float4*)(xc + (size_t)(b * L + t) * DI + d) = o;
}

// ---------------------------------------------------------------------------
// Fused selective scan. Block = 16 d-channels x 16 states. grid=(DI/16, B).
// y[b,t,d] = (sum_s h*C + D*xc) * silu(z);  h = exp(dt*A)*h + dt*B*xc
// ---------------------------------------------------------------------------
__global__ __launch_bounds__(256)
void scan_kernel(const float* __restrict__ dt, const float* __restrict__ dbl,
                 const float* __restrict__ xc, const float* __restrict__ xz,
                 const float* __restrict__ A_log, const float* __restrict__ Dp,
                 float* __restrict__ y, int L, int instShift)
{
    __shared__ float sdt[16][16], sxc[16][16], szb[16][16], sB[16][16], sC[16][16];
    const int b = blockIdx.y;
    const int chunk = blockIdx.x;
    const int inst = b >> instShift;
    const int tid = threadIdx.x;
    const int dl = tid >> 4, s = tid & 15;
    const int d = chunk * 16 + dl;
    const float Aneg = -expf(A_log[((size_t)inst * DI + d) * DS + s]);
    const float Dd = Dp[(size_t)inst * DI + d];
    float h = 0.f;
    const size_t rowbase = (size_t)b * L;
    for (int t0 = 0; t0 < L; t0 += 16) {
        {
            const int tt = tid >> 4, cc = tid & 15;
            const size_t r = rowbase + t0 + tt;
            sdt[tt][cc] = dt[r * DI + chunk*16 + cc];
            sxc[tt][cc] = xc[r * DI + chunk*16 + cc];
            szb[tt][cc] = xz[r * 3072 + DI + chunk*16 + cc];
            sB [tt][cc] = dbl[r * 80 + 48 + cc];
            sC [tt][cc] = dbl[r * 80 + 64 + cc];
        }
        __syncthreads();
#pragma unroll
        for (int tt = 0; tt < 16; ++tt) {
            const float dtv = sdt[tt][dl];
            const float xcv = sxc[tt][dl];
            const float dA = __expf(dtv * Aneg);
            h = dA * h + dtv * sB[tt][s] * xcv;
            float p = h * sC[tt][s];
            p += __shfl_xor(p, 1);
            p += __shfl_xor(p, 2);
            p += __shfl_xor(p, 4);
            p += __shfl_xor(p, 8);
            if (s == 0) {
                const float zv = szb[tt][dl];
                y[(rowbase + t0 + tt) * DI + d] = (p + Dd * xcv) * (zv / (1.f + expf(-zv)));
            }
        }
        __syncthreads();
    }
}

// ---------------------------------------------------------------------------
// Local-window cross attention: 2-3 keys per query. One block (64 thr) per (b,i).
// q:(768,768)  kv:(2048,1536) [k | v]  o:(768,768)
// ---------------------------------------------------------------------------
__global__ void attn_kernel(const float* __restrict__ q, const float* __restrict__ kv,
                            float* __restrict__ o)
{
    const int bi = blockIdx.x;
    const int b = bi / NQ, i = bi % NQ;
    const int tid = threadIdx.x;
    const int h = tid >> 2, r = tid & 3;
    int start, len;
    if (i < 256) { start = 3*i; len = 3; } else { start = 2*i + 256; len = 2; }
    const float* qp = q + (size_t)bi * DIMQ + h*48 + r*12;
    float qv[12];
#pragma unroll
    for (int u = 0; u < 12; ++u) qv[u] = qp[u];
    float s[3] = {-1e30f, -1e30f, -1e30f};
    for (int j = 0; j < len; ++j) {
        const float* kp = kv + (size_t)(b*LSEQ + start + j) * 1536 + h*48 + r*12;
        float p = 0.f;
#pragma unroll
        for (int u = 0; u < 12; ++u) p += qv[u] * kp[u];
        p += __shfl_xor(p, 1);
        p += __shfl_xor(p, 2);
        s[j] = p * 0.14433756729740644f;   // 1/sqrt(48)
    }
    const float mx = fmaxf(s[0], fmaxf(s[1], s[2]));
    float e[3];
    e[0] = expf(s[0]-mx); e[1] = expf(s[1]-mx); e[2] = expf(s[2]-mx);
    const float inv = 1.f / (e[0] + e[1] + e[2]);
    float ov[12] = {};
    for (int j = 0; j < len; ++j) {
        const float w = e[j] * inv;
        const float* vp = kv + (size_t)(b*LSEQ + start + j) * 1536 + 768 + h*48 + r*12;
#pragma unroll
        for (int u = 0; u < 12; ++u) ov[u] += w * vp[u];
    }
    float* op = o + (size_t)bi * DIMQ + h*48 + r*12;
#pragma unroll
    for (int u = 0; u < 12; ++u) op[u] = ov[u];
}

// ---------------------------------------------------------------------------
// small utility kernels
// ---------------------------------------------------------------------------
__global__ void flip_kernel(float* __restrict__ X2)   // rows 2048..4095 = batch-flipped rows 0..2047
{
    const int idx = blockIdx.x * 256 + threadIdx.x;
    if (idx >= 2*1024*192) return;
    const int d4 = idx % 192;
    const int t  = (idx / 192) % 1024;
    const int b  = idx / (192 * 1024);
    const size_t dst = ((size_t)((2+b)*1024 + t)) * DIMQ + d4*4;
    const size_t src = ((size_t)(b*1024 + (1023 - t))) * DIMQ + d4*4;
    *(float4*)(X2 + dst) = *(const float4*)(X2 + src);
}

__global__ void combine_kernel(const float* __restrict__ oe, const float* __restrict__ feats,
                               float* __restrict__ c)
{
    const int idx = blockIdx.x * 256 + threadIdx.x;
    if (idx >= 2*1024*192) return;
    const int d4 = idx % 192;
    const int t  = (idx / 192) % 1024;
    const int b  = idx / (192 * 1024);
    const size_t fw = ((size_t)(b*1024 + t)) * DIMQ + d4*4;
    const size_t bw = ((size_t)((2+b)*1024 + (1023 - t))) * DIMQ + d4*4;
    const float4 a = *(const float4*)(oe + fw);
    const float4 bb = *(const float4*)(oe + bw);
    const float4 f = *(const float4*)(feats + fw);
    float4 o;
    o.x = a.x + bb.x + f.x; o.y = a.y + bb.y + f.y;
    o.z = a.z + bb.z + f.z; o.w = a.w + bb.w + f.w;
    *(float4*)(c + fw) = o;
}

__global__ void qinit_kernel(float* __restrict__ x, const float* __restrict__ queries)
{
    const int idx = blockIdx.x * 256 + threadIdx.x;
    if (idx >= 2*NQ*192) return;
    const int d4 = idx % 192;
    const int i  = (idx / 192) % NQ;
    *(float4*)(x + (size_t)idx * 4) = *(const float4*)(queries + ((size_t)i * DIMQ + d4*4));
}

// ---------------------------------------------------------------------------
extern "C" void kernel_launch(void* const* d_in, const int* in_sizes, int n_in,
                              void* d_out, int out_size, void* d_ws, size_t ws_size,
                              hipStream_t stream) {
    const float* img_emb  = (const float*)d_in[0];
    const float* queries  = (const float*)d_in[1];
    const float* vis_w    = (const float*)d_in[2];
    const float* vis_b    = (const float*)d_in[3];
    const float* lnv_g    = (const float*)d_in[4];
    const float* lnv_b    = (const float*)d_in[5];
    const float* m_in_w   = (const float*)d_in[6];
    const float* m_conv_w = (const float*)d_in[7];
    const float* m_conv_b = (const float*)d_in[8];
    const float* m_xp_w   = (const float*)d_in[9];
    const float* m_dt_w   = (const float*)d_in[10];
    const float* m_dt_b   = (const float*)d_in[11];
    const float* m_A_log  = (const float*)d_in[12];
    const float* m_D      = (const float*)d_in[13];
    const float* m_out_w  = (const float*)d_in[14];
    const float* sn_g     = (const float*)d_in[15];
    const float* sn_b     = (const float*)d_in[16];
    const float* a_in_w   = (const float*)d_in[17];
    const float* a_in_b   = (const float*)d_in[18];
    const float* a_out_w  = (const float*)d_in[19];
    const float* a_out_b  = (const float*)d_in[20];
    const float* cr_w     = (const float*)d_in[21];
    const float* cr_b     = (const float*)d_in[22];
    float* out = (float*)d_out;

    float* ws = (float*)d_ws;
    float* X2   = ws; ws += (size_t)4*1024*768;    // [feats(2); flip(feats)(2)]
    float* xzb  = ws; ws += (size_t)4*1024*3072;
    float* xcb  = ws; ws += (size_t)4*1024*1536;
    float* dblb = ws; ws += (size_t)4*1024*80;
    float* dtb  = ws; ws += (size_t)4*1024*1536;
    float* yb   = ws; ws += (size_t)4*1024*1536;
    float* oe   = ws; ws += (size_t)4*1024*768;    // vis tmp / enc out / kv (2048x1536)
    float* cbuf = ws; ws += (size_t)2*1024*768;
    float* xbuf = ws; ws += (size_t)2*NQ*768;
    float* xn   = ws; ws += (size_t)2*NQ*768;
    float* x1   = ws; ws += (size_t)2*NQ*768;
    float* qb   = ws; ws += (size_t)2*NQ*768;
    float* ob   = ws; ws += (size_t)2*NQ*768;
    float* scb  = ws; ws += (size_t)2*NQ*768;

    auto G = [&](const float* A, const float* B, float* C, const float* bias, const float* addT,
                 int M, int N, int K, int lda, int ldb, int ldc,
                 long long sA, long long sB, long long sC, long long sBias, int nz, int flags) {
        dim3 grid((M + 127) / 128, (N + 127) / 128, nz);
        gemm_kernel<<<grid, 256, 0, stream>>>(A, B, C, bias, addT,
                                              M, N, K, lda, ldb, ldc, sA, sB, sC, sBias, flags);
    };

    // ---- vision proj + LN + build stacked [feats; flip(feats)] ----
    G(img_emb, vis_w, oe, vis_b, nullptr, 2048, 768, 1024, 1024, 1024, 768, 0,0,0,0, 1, GF_BIAS);
    ln_kernel<<<512, 256, 0, stream>>>(oe, X2, lnv_g, lnv_b, 2048);
    flip_kernel<<<(2*1024*192 + 255)/256, 256, 0, stream>>>(X2);
    qinit_kernel<<<(2*NQ*192 + 255)/256, 256, 0, stream>>>(xbuf, queries);

    // ---- encoder mambas (fwd + bwd batched: 2 weight groups over 4 batch rows) ----
    G(X2, m_in_w, xzb, nullptr, nullptr, 2048, 3072, 768, 768, 768, 3072,
      2048LL*768, 3072LL*768, 2048LL*3072, 0, 2, 0);
    conv_kernel<<<(4*1024*384 + 255)/256, 256, 0, stream>>>(xzb, xcb, m_conv_w, m_conv_b, 4, 1024, 1);
    G(xcb, m_xp_w, dblb, nullptr, nullptr, 2048, 80, 1536, 1536, 1536, 80,
      2048LL*1536, 80LL*1536, 2048LL*80, 0, 2, 0);
    G(dblb, m_dt_w, dtb, m_dt_b, nullptr, 2048, 1536, 48, 80, 48, 1536,
      2048LL*80, 1536LL*48, 2048LL*1536, 1536, 2, GF_BIAS | GF_SOFTPLUS);
    scan_kernel<<<dim3(96, 4), 256, 0, stream>>>(dtb, dblb, xcb, xzb, m_A_log, m_D, yb, 1024, 1);
    G(yb, m_out_w, oe, nullptr, nullptr, 2048, 768, 1536, 1536, 1536, 768,
      2048LL*1536, 768LL*1536, 2048LL*768, 0, 2, 0);
    combine_kernel<<<(2*1024*192 + 255)/256, 256, 0, stream>>>(oe, X2, cbuf);

    // ---- 12 blocks ----
    for (int l = 0; l < NBK; ++l) {
        const int li = l + 2;
        ln_kernel<<<192, 256, 0, stream>>>(xbuf, xn, sn_g + (size_t)l*768, sn_b + (size_t)l*768, 768);
        G(xn, m_in_w + (size_t)li*3072*768, xzb, nullptr, nullptr,
          768, 3072, 768, 768, 768, 3072, 0,0,0,0, 1, 0);
        conv_kernel<<<(2*NQ*384 + 255)/256, 256, 0, stream>>>(
            xzb, xcb, m_conv_w + (size_t)li*DI*4, m_conv_b + (size_t)li*DI, 2, NQ, 8);
        G(xcb, m_xp_w + (size_t)li*80*1536, dblb, nullptr, nullptr,
          768, 80, 1536, 1536, 1536, 80, 0,0,0,0, 1, 0);
        G(dblb, m_dt_w + (size_t)li*1536*48, dtb, m_dt_b + (size_t)li*1536, nullptr,
          768, 1536, 48, 80, 48, 1536, 0,0,0,0, 1, GF_BIAS | GF_SOFTPLUS);
        scan_kernel<<<dim3(96, 2), 256, 0, stream>>>(
            dtb, dblb, xcb, xzb, m_A_log + (size_t)li*DI*DS, m_D + (size_t)li*DI, yb, NQ, 8);
        G(yb, m_out_w + (size_t)li*768*1536, x1, nullptr, xn,
          768, 768, 1536, 1536, 1536, 768, 0,0,0,0, 1, GF_ADDT);     // x1 = mamba_out + xn
        // attention
        G(x1, a_in_w + (size_t)l*2304*768, qb, a_in_b + (size_t)l*2304, nullptr,
          768, 768, 768, 768, 768, 768, 0,0,0,0, 1, GF_BIAS);
        G(cbuf, a_in_w + (size_t)l*2304*768 + 768*768, oe, a_in_b + (size_t)l*2304 + 768, nullptr,
          2048, 1536, 768, 768, 768, 1536, 0,0,0,0, 1, GF_BIAS);     // kv = [k|v]
        attn_kernel<<<2*NQ, 64, 0, stream>>>(qb, oe, ob);
        G(ob, a_out_w + (size_t)l*768*768, scb, a_out_b + (size_t)l*768, nullptr,
          768, 768, 768, 768, 768, 768, 0,0,0,0, 1, GF_BIAS);
        // x = [x1, score] @ cross_w^T + cross_b  (two K=768 GEMMs into same C)
        float* dst = (l == NBK - 1) ? out : xbuf;
        G(x1, cr_w + (size_t)l*768*1536, dst, cr_b + (size_t)l*768, nullptr,
          768, 768, 768, 768, 1536, 768, 0,0,0,0, 1, GF_BIAS);
        G(scb, cr_w + (size_t)l*768*1536 + 768, dst, nullptr, nullptr,
          768, 768, 768, 768, 1536, 768, 0,0,0,0, 1, GF_ACCUM);
    }
}

// Round 2
// 10692.440 us; speedup vs baseline: 1.0731x; 1.0731x over previous
//
#include <hip/hip_runtime.h>
#include <hip/hip_bf16.h>

// ---- model constants ----
#define DIMQ 768
#define D_IN 1024
#define NQ 384
#define NBK 12
#define BATCH 2
#define LSEQ 1024
#define DI 1536
#define DS 16
#define DTR 48
#define NH 16
#define HD 48

typedef __attribute__((ext_vector_type(8))) short short8;
typedef __attribute__((ext_vector_type(4))) float f32x4;

#define GF_BIAS 1
#define GF_SOFTPLUS 2
#define GF_ADDT 4
#define GF_ACCUM 8

#define LOG2E 1.4426950408889634f

__device__ __forceinline__ unsigned short f2bf(float f) {
    unsigned int u = __builtin_bit_cast(unsigned int, f);
    u = (u + 0x7FFFu + ((u >> 16) & 1u)) >> 16;
    return (unsigned short)u;
}
__device__ __forceinline__ float bf2f(unsigned short h) {
    unsigned int u = ((unsigned int)h) << 16;
    return __builtin_bit_cast(float, u);
}

// ---------------------------------------------------------------------------
// GEMM: C[M,N] = A[M,K] * B[N,K]^T  (+bias/softplus/add), split-bf16 (3 MFMA)
// 128x128 tile, 4 waves, 16x16x32 bf16 MFMA. grid.z = batched groups.
// ---------------------------------------------------------------------------
__global__ void gemm_kernel(const float* __restrict__ Ag, const float* __restrict__ Bg,
                            float* __restrict__ Cg, const float* __restrict__ biasg,
                            const float* __restrict__ addT,
                            int M, int N, int K, int lda, int ldb, int ldc,
                            long long sA, long long sB, long long sC, long long sBias,
                            int flags)
{
    __shared__ __align__(16) unsigned short As[2][128][40];   // [hi/lo][row][k] +pad
    __shared__ __align__(16) unsigned short Bs[2][128][40];

    const int z = blockIdx.z;
    const float* A = Ag + (size_t)z * sA;
    const float* B = Bg + (size_t)z * sB;
    float* C = Cg + (size_t)z * sC;

    const int mBase = blockIdx.x * 128;
    const int nBase = blockIdx.y * 128;
    const int tid  = threadIdx.x;
    const int row2 = tid >> 1;       // 0..127
    const int half = tid & 1;        // which 16-wide k half
    const int lane = tid & 63;
    const int wave = tid >> 6;
    const int wm = (wave & 1) * 64;
    const int wn = (wave >> 1) * 64;
    const int lm = lane & 15;
    const int lq = lane >> 4;

    f32x4 acc[4][4] = {};

    const int ktiles = (K + 31) >> 5;
    for (int t = 0; t < ktiles; ++t) {
        const int kb = t * 32 + half * 16;
        // ---- stage A (128x32 f32 -> bf16 hi/lo) ----
        {
            const int gr = mBase + row2;
            const bool rowok = gr < M;
            const float* src = A + (size_t)gr * lda;
            float v[16];
#pragma unroll
            for (int q = 0; q < 4; ++q) {
                const int col = kb + q * 4;
                float4 t4 = make_float4(0.f, 0.f, 0.f, 0.f);
                if (rowok && col < K) t4 = *(const float4*)(src + col);
                v[q*4+0]=t4.x; v[q*4+1]=t4.y; v[q*4+2]=t4.z; v[q*4+3]=t4.w;
            }
            unsigned short hh[16], ll[16];
#pragma unroll
            for (int i = 0; i < 16; ++i) {
                hh[i] = f2bf(v[i]);
                ll[i] = f2bf(v[i] - bf2f(hh[i]));
            }
            unsigned short* dh = &As[0][row2][half*16];
            unsigned short* dl = &As[1][row2][half*16];
#pragma unroll
            for (int c = 0; c < 2; ++c) {
                short8 ph, pl;
#pragma unroll
                for (int j = 0; j < 8; ++j) { ph[j] = (short)hh[c*8+j]; pl[j] = (short)ll[c*8+j]; }
                *(short8*)(dh + c*8) = ph;
                *(short8*)(dl + c*8) = pl;
            }
        }
        // ---- stage B (128x32) ----
        {
            const int gr = nBase + row2;
            const bool rowok = gr < N;
            const float* src = B + (size_t)gr * ldb;
            float v[16];
#pragma unroll
            for (int q = 0; q < 4; ++q) {
                const int col = kb + q * 4;
                float4 t4 = make_float4(0.f, 0.f, 0.f, 0.f);
                if (rowok && col < K) t4 = *(const float4*)(src + col);
                v[q*4+0]=t4.x; v[q*4+1]=t4.y; v[q*4+2]=t4.z; v[q*4+3]=t4.w;
            }
            unsigned short hh[16], ll[16];
#pragma unroll
            for (int i = 0; i < 16; ++i) {
                hh[i] = f2bf(v[i]);
                ll[i] = f2bf(v[i] - bf2f(hh[i]));
            }
            unsigned short* dh = &Bs[0][row2][half*16];
            unsigned short* dl = &Bs[1][row2][half*16];
#pragma unroll
            for (int c = 0; c < 2; ++c) {
                short8 ph, pl;
#pragma unroll
                for (int j = 0; j < 8; ++j) { ph[j] = (short)hh[c*8+j]; pl[j] = (short)ll[c*8+j]; }
                *(short8*)(dh + c*8) = ph;
                *(short8*)(dl + c*8) = pl;
            }
        }
        __syncthreads();
        // ---- compute ----
        short8 ah[4], al[4], bh[4], bl[4];
#pragma unroll
        for (int i = 0; i < 4; ++i) {
            ah[i] = *(const short8*)&As[0][wm + i*16 + lm][lq*8];
            al[i] = *(const short8*)&As[1][wm + i*16 + lm][lq*8];
            bh[i] = *(const short8*)&Bs[0][wn + i*16 + lm][lq*8];
            bl[i] = *(const short8*)&Bs[1][wn + i*16 + lm][lq*8];
        }
#pragma unroll
        for (int i = 0; i < 4; ++i)
#pragma unroll
            for (int j = 0; j < 4; ++j) {
                acc[i][j] = __builtin_amdgcn_mfma_f32_16x16x32_bf16(ah[i], bh[j], acc[i][j], 0, 0, 0);
                acc[i][j] = __builtin_amdgcn_mfma_f32_16x16x32_bf16(ah[i], bl[j], acc[i][j], 0, 0, 0);
                acc[i][j] = __builtin_amdgcn_mfma_f32_16x16x32_bf16(al[i], bh[j], acc[i][j], 0, 0, 0);
            }
        __syncthreads();
    }

    // ---- epilogue: C/D layout col=lane&15, row=(lane>>4)*4+r ----
#pragma unroll
    for (int i = 0; i < 4; ++i)
#pragma unroll
        for (int j = 0; j < 4; ++j)
#pragma unroll
            for (int r = 0; r < 4; ++r) {
                const int m = mBase + wm + i*16 + lq*4 + r;
                const int n = nBase + wn + j*16 + lm;
                if (m < M && n < N) {
                    float v = acc[i][j][r];
                    if (flags & GF_BIAS)     v += biasg[(size_t)z * sBias + n];
                    if (flags & GF_SOFTPLUS) v = (v > 20.f) ? v : log1pf(expf(v));
                    if (flags & GF_ADDT)     v += addT[(size_t)m * ldc + n];
                    if (flags & GF_ACCUM)    v += C[(size_t)m * ldc + n];
                    C[(size_t)m * ldc + n] = v;
                }
            }
}

// ---------------------------------------------------------------------------
// LayerNorm over last dim 768. One wave per row.
// ---------------------------------------------------------------------------
__global__ void ln_kernel(const float* __restrict__ in, float* __restrict__ out,
                          const float* __restrict__ g, const float* __restrict__ b, int rows)
{
    const int row = blockIdx.x * 4 + (threadIdx.x >> 6);
    const int lane = threadIdx.x & 63;
    if (row >= rows) return;
    const float* p = in + (size_t)row * DIMQ;
    float v[12], s = 0.f, s2 = 0.f;
#pragma unroll
    for (int j = 0; j < 12; ++j) {
        v[j] = p[j*64 + lane];
        s += v[j];
        s2 += v[j]*v[j];
    }
#pragma unroll
    for (int o = 32; o; o >>= 1) { s += __shfl_xor(s, o); s2 += __shfl_xor(s2, o); }
    const float mean = s * (1.f/768.f);
    const float var  = s2 * (1.f/768.f) - mean*mean;
    const float inv  = rsqrtf(var + 1e-5f);
    float* q = out + (size_t)row * DIMQ;
#pragma unroll
    for (int j = 0; j < 12; ++j) {
        const int c = j*64 + lane;
        q[c] = (v[j] - mean) * inv * g[c] + b[c];
    }
}

// ---------------------------------------------------------------------------
// Depthwise causal conv1d (DC=4) + silu.  xi = xz[:, :DI] (row stride 3072).
// ---------------------------------------------------------------------------
__global__ void conv_kernel(const float* __restrict__ xz, float* __restrict__ xc,
                            const float* __restrict__ cw, const float* __restrict__ cb,
                            int Bn, int L, int instShift)
{
    const int idx = blockIdx.x * 256 + threadIdx.x;
    const int total = Bn * L * (DI/4);
    if (idx >= total) return;
    const int d4 = idx % (DI/4);
    const int t  = (idx / (DI/4)) % L;
    const int b  = idx / (L * (DI/4));
    const int inst = b >> instShift;
    const int d = d4 * 4;
    const float* base = xz + (size_t)(b * L) * 3072 + d;
    const float4 w0 = *(const float4*)(cw + (size_t)(inst*DI + d + 0) * 4);
    const float4 w1 = *(const float4*)(cw + (size_t)(inst*DI + d + 1) * 4);
    const float4 w2 = *(const float4*)(cw + (size_t)(inst*DI + d + 2) * 4);
    const float4 w3 = *(const float4*)(cw + (size_t)(inst*DI + d + 3) * 4);
    float4 acc = *(const float4*)(cb + (size_t)inst*DI + d);
    float4 xv[4];
#pragma unroll
    for (int j = 0; j < 4; ++j) {
        const int tt = t - 3 + j;
        xv[j] = (tt >= 0) ? *(const float4*)(base + (size_t)tt * 3072) : make_float4(0,0,0,0);
    }
    acc.x += xv[0].x*w0.x + xv[1].x*w0.y + xv[2].x*w0.z + xv[3].x*w0.w;
    acc.y += xv[0].y*w1.x + xv[1].y*w1.y + xv[2].y*w1.z + xv[3].y*w1.w;
    acc.z += xv[0].z*w2.x + xv[1].z*w2.y + xv[2].z*w2.z + xv[3].z*w2.w;
    acc.w += xv[0].w*w3.x + xv[1].w*w3.y + xv[2].w*w3.z + xv[3].w*w3.w;
    float4 o;
    o.x = acc.x / (1.f + expf(-acc.x));
    o.y = acc.y / (1.f + expf(-acc.y));
    o.z = acc.z / (1.f + expf(-acc.z));
    o.w = acc.w / (1.f + expf(-acc.w));
    *(float4*)(xc + (size_t)(b * L + t) * DI + d) = o;
}

// ---------------------------------------------------------------------------
// Chunked selective scan, 3 passes. Thread owns one d-channel, h[16] in regs,
// no cross-lane ops. Chunk prefix product uses exp(A_s * sum(dt)) identity.
// ---------------------------------------------------------------------------
__global__ __launch_bounds__(256)
void scan_p1(const float* __restrict__ dt, const float* __restrict__ dbl,
             const float* __restrict__ xc, const float* __restrict__ A_log,
             float* __restrict__ hend, float* __restrict__ sumdt,
             int L, int CL, int Bn, int instShift)
{
    const int d = blockIdx.x * 256 + threadIdx.x;
    const int b = blockIdx.y;
    const int c = blockIdx.z;
    const int inst = b >> instShift;
    const float* ap = A_log + ((size_t)inst * DI + d) * DS;
    float A2[16];
#pragma unroll
    for (int s = 0; s < 16; ++s) A2[s] = -expf(ap[s]) * LOG2E;
    float h[16] = {};
    float sd = 0.f;
    const int t0 = c * CL;
    for (int t = t0; t < t0 + CL; ++t) {
        const size_t row = (size_t)b * L + t;
        const float dtv = dt[row * DI + d];
        const float xcv = xc[row * DI + d];
        float Bv[16];
        *(float4*)(Bv + 0)  = *(const float4*)(dbl + row * 80 + 48);
        *(float4*)(Bv + 4)  = *(const float4*)(dbl + row * 80 + 52);
        *(float4*)(Bv + 8)  = *(const float4*)(dbl + row * 80 + 56);
        *(float4*)(Bv + 12) = *(const float4*)(dbl + row * 80 + 60);
        sd += dtv;
        const float bx = dtv * xcv;
#pragma unroll
        for (int s = 0; s < 16; ++s)
            h[s] = exp2f(dtv * A2[s]) * h[s] + bx * Bv[s];
    }
    float* hp = hend + (((size_t)c * Bn + b) * DI + d) * DS;
#pragma unroll
    for (int s = 0; s < 16; s += 4)
        *(float4*)(hp + s) = make_float4(h[s], h[s+1], h[s+2], h[s+3]);
    sumdt[((size_t)c * Bn + b) * DI + d] = sd;
}

__global__ void scan_p2(const float* __restrict__ hend, const float* __restrict__ sumdt,
                        const float* __restrict__ A_log, float* __restrict__ hstart,
                        int NC, int Bn, int instShift)
{
    const int gid = blockIdx.x * 256 + threadIdx.x;
    const int s = gid & 15;
    const int rem = gid >> 4;
    const int d = rem % DI;
    const int b = rem / DI;
    const int inst = b >> instShift;
    const float A2 = -expf(A_log[((size_t)inst * DI + d) * DS + s]) * LOG2E;
    float carry = 0.f;
    for (int c = 0; c < NC; ++c) {
        const size_t off = (((size_t)c * Bn + b) * DI + d) * DS + s;
        hstart[off] = carry;
        carry = exp2f(A2 * sumdt[((size_t)c * Bn + b) * DI + d]) * carry + hend[off];
    }
}

__global__ __launch_bounds__(256)
void scan_p3(const float* __restrict__ dt, const float* __restrict__ dbl,
             const float* __restrict__ xc, const float* __restrict__ xz,
             const float* __restrict__ A_log, const float* __restrict__ Dp,
             const float* __restrict__ hstart, float* __restrict__ y,
             int L, int CL, int Bn, int instShift)
{
    const int d = blockIdx.x * 256 + threadIdx.x;
    const int b = blockIdx.y;
    const int c = blockIdx.z;
    const int inst = b >> instShift;
    const float* ap = A_log + ((size_t)inst * DI + d) * DS;
    float A2[16];
#pragma unroll
    for (int s = 0; s < 16; ++s) A2[s] = -expf(ap[s]) * LOG2E;
    const float Dd = Dp[(size_t)inst * DI + d];
    float h[16];
    const float* hp = hstart + (((size_t)c * Bn + b) * DI + d) * DS;
#pragma unroll
    for (int s = 0; s < 16; s += 4) {
        const float4 t4 = *(const float4*)(hp + s);
        h[s] = t4.x; h[s+1] = t4.y; h[s+2] = t4.z; h[s+3] = t4.w;
    }
    const int t0 = c * CL;
    for (int t = t0; t < t0 + CL; ++t) {
        const size_t row = (size_t)b * L + t;
        const float dtv = dt[row * DI + d];
        const float xcv = xc[row * DI + d];
        const float zv  = xz[row * 3072 + DI + d];
        float Bv[16], Cv[16];
        *(float4*)(Bv + 0)  = *(const float4*)(dbl + row * 80 + 48);
        *(float4*)(Bv + 4)  = *(const float4*)(dbl + row * 80 + 52);
        *(float4*)(Bv + 8)  = *(const float4*)(dbl + row * 80 + 56);
        *(float4*)(Bv + 12) = *(const float4*)(dbl + row * 80 + 60);
        *(float4*)(Cv + 0)  = *(const float4*)(dbl + row * 80 + 64);
        *(float4*)(Cv + 4)  = *(const float4*)(dbl + row * 80 + 68);
        *(float4*)(Cv + 8)  = *(const float4*)(dbl + row * 80 + 72);
        *(float4*)(Cv + 12) = *(const float4*)(dbl + row * 80 + 76);
        const float bx = dtv * xcv;
#pragma unroll
        for (int s = 0; s < 16; ++s)
            h[s] = exp2f(dtv * A2[s]) * h[s] + bx * Bv[s];
        float p0 = 0.f, p1 = 0.f, p2 = 0.f, p3 = 0.f;
#pragma unroll
        for (int s = 0; s < 4; ++s) {
            p0 += h[s]      * Cv[s];
            p1 += h[s + 4]  * Cv[s + 4];
            p2 += h[s + 8]  * Cv[s + 8];
            p3 += h[s + 12] * Cv[s + 12];
        }
        const float p = (p0 + p1) + (p2 + p3);
        y[row * DI + d] = (p + Dd * xcv) * (zv / (1.f + expf(-zv)));
    }
}

// ---------------------------------------------------------------------------
// Local-window cross attention: 2-3 keys per query. One block (64 thr) per (b,i).
// ---------------------------------------------------------------------------
__global__ void attn_kernel(const float* __restrict__ q, const float* __restrict__ kv,
                            float* __restrict__ o)
{
    const int bi = blockIdx.x;
    const int b = bi / NQ, i = bi % NQ;
    const int tid = threadIdx.x;
    const int h = tid >> 2, r = tid & 3;
    int start, len;
    if (i < 256) { start = 3*i; len = 3; } else { start = 2*i + 256; len = 2; }
    const float* qp = q + (size_t)bi * DIMQ + h*48 + r*12;
    float qv[12];
#pragma unroll
    for (int u = 0; u < 12; ++u) qv[u] = qp[u];
    float s[3] = {-1e30f, -1e30f, -1e30f};
    for (int j = 0; j < len; ++j) {
        const float* kp = kv + (size_t)(b*LSEQ + start + j) * 1536 + h*48 + r*12;
        float p = 0.f;
#pragma unroll
        for (int u = 0; u < 12; ++u) p += qv[u] * kp[u];
        p += __shfl_xor(p, 1);
        p += __shfl_xor(p, 2);
        s[j] = p * 0.14433756729740644f;   // 1/sqrt(48)
    }
    const float mx = fmaxf(s[0], fmaxf(s[1], s[2]));
    float e[3];
    e[0] = expf(s[0]-mx); e[1] = expf(s[1]-mx); e[2] = expf(s[2]-mx);
    const float inv = 1.f / (e[0] + e[1] + e[2]);
    float ov[12] = {};
    for (int j = 0; j < len; ++j) {
        const float w = e[j] * inv;
        const float* vp = kv + (size_t)(b*LSEQ + start + j) * 1536 + 768 + h*48 + r*12;
#pragma unroll
        for (int u = 0; u < 12; ++u) ov[u] += w * vp[u];
    }
    float* op = o + (size_t)bi * DIMQ + h*48 + r*12;
#pragma unroll
    for (int u = 0; u < 12; ++u) op[u] = ov[u];
}

// ---------------------------------------------------------------------------
// small utility kernels
// ---------------------------------------------------------------------------
__global__ void flip_kernel(float* __restrict__ X2)
{
    const int idx = blockIdx.x * 256 + threadIdx.x;
    if (idx >= 2*1024*192) return;
    const int d4 = idx % 192;
    const int t  = (idx / 192) % 1024;
    const int b  = idx / (192 * 1024);
    const size_t dst = ((size_t)((2+b)*1024 + t)) * DIMQ + d4*4;
    const size_t src = ((size_t)(b*1024 + (1023 - t))) * DIMQ + d4*4;
    *(float4*)(X2 + dst) = *(const float4*)(X2 + src);
}

__global__ void combine_kernel(const float* __restrict__ oe, const float* __restrict__ feats,
                               float* __restrict__ c)
{
    const int idx = blockIdx.x * 256 + threadIdx.x;
    if (idx >= 2*1024*192) return;
    const int d4 = idx % 192;
    const int t  = (idx / 192) % 1024;
    const int b  = idx / (192 * 1024);
    const size_t fw = ((size_t)(b*1024 + t)) * DIMQ + d4*4;
    const size_t bw = ((size_t)((2+b)*1024 + (1023 - t))) * DIMQ + d4*4;
    const float4 a = *(const float4*)(oe + fw);
    const float4 bb = *(const float4*)(oe + bw);
    const float4 f = *(const float4*)(feats + fw);
    float4 o;
    o.x = a.x + bb.x + f.x; o.y = a.y + bb.y + f.y;
    o.z = a.z + bb.z + f.z; o.w = a.w + bb.w + f.w;
    *(float4*)(c + fw) = o;
}

__global__ void qinit_kernel(float* __restrict__ x, const float* __restrict__ queries)
{
    const int idx = blockIdx.x * 256 + threadIdx.x;
    if (idx >= 2*NQ*192) return;
    const int d4 = idx % 192;
    const int i  = (idx / 192) % NQ;
    *(float4*)(x + (size_t)idx * 4) = *(const float4*)(queries + ((size_t)i * DIMQ + d4*4));
}

// ---------------------------------------------------------------------------
extern "C" void kernel_launch(void* const* d_in, const int* in_sizes, int n_in,
                              void* d_out, int out_size, void* d_ws, size_t ws_size,
                              hipStream_t stream) {
    const float* img_emb  = (const float*)d_in[0];
    const float* queries  = (const float*)d_in[1];
    const float* vis_w    = (const float*)d_in[2];
    const float* vis_b    = (const float*)d_in[3];
    const float* lnv_g    = (const float*)d_in[4];
    const float* lnv_b    = (const float*)d_in[5];
    const float* m_in_w   = (const float*)d_in[6];
    const float* m_conv_w = (const float*)d_in[7];
    const float* m_conv_b = (const float*)d_in[8];
    const float* m_xp_w   = (const float*)d_in[9];
    const float* m_dt_w   = (const float*)d_in[10];
    const float* m_dt_b   = (const float*)d_in[11];
    const float* m_A_log  = (const float*)d_in[12];
    const float* m_D      = (const float*)d_in[13];
    const float* m_out_w  = (const float*)d_in[14];
    const float* sn_g     = (const float*)d_in[15];
    const float* sn_b     = (const float*)d_in[16];
    const float* a_in_w   = (const float*)d_in[17];
    const float* a_in_b   = (const float*)d_in[18];
    const float* a_out_w  = (const float*)d_in[19];
    const float* a_out_b  = (const float*)d_in[20];
    const float* cr_w     = (const float*)d_in[21];
    const float* cr_b     = (const float*)d_in[22];
    float* out = (float*)d_out;

    float* ws = (float*)d_ws;
    float* X2   = ws; ws += (size_t)4*1024*768;
    float* xzb  = ws; ws += (size_t)4*1024*3072;
    float* xcb  = ws; ws += (size_t)4*1024*1536;
    float* dblb = ws; ws += (size_t)4*1024*80;
    float* dtb  = ws; ws += (size_t)4*1024*1536;
    float* yb   = ws; ws += (size_t)4*1024*1536;
    float* oe   = ws; ws += (size_t)4*1024*768;    // vis tmp / enc out / kv / scan scratch
    float* cbuf = ws; ws += (size_t)2*1024*768;
    float* xbuf = ws; ws += (size_t)2*NQ*768;
    float* xn   = ws; ws += (size_t)2*NQ*768;
    float* x1   = ws; ws += (size_t)2*NQ*768;
    float* qb   = ws; ws += (size_t)2*NQ*768;
    float* ob   = ws; ws += (size_t)2*NQ*768;
    float* scb  = ws; ws += (size_t)2*NQ*768;

    auto G = [&](const float* A, const float* B, float* C, const float* bias, const float* addT,
                 int M, int N, int K, int lda, int ldb, int ldc,
                 long long sA, long long sB, long long sC, long long sBias, int nz, int flags) {
        dim3 grid((M + 127) / 128, (N + 127) / 128, nz);
        gemm_kernel<<<grid, 256, 0, stream>>>(A, B, C, bias, addT,
                                              M, N, K, lda, ldb, ldc, sA, sB, sC, sBias, flags);
    };

    // ---- vision proj + LN + build stacked [feats; flip(feats)] ----
    G(img_emb, vis_w, oe, vis_b, nullptr, 2048, 768, 1024, 1024, 1024, 768, 0,0,0,0, 1, GF_BIAS);
    ln_kernel<<<512, 256, 0, stream>>>(oe, X2, lnv_g, lnv_b, 2048);
    flip_kernel<<<(2*1024*192 + 255)/256, 256, 0, stream>>>(X2);
    qinit_kernel<<<(2*NQ*192 + 255)/256, 256, 0, stream>>>(xbuf, queries);

    // ---- encoder mambas (fwd + bwd batched) ----
    G(X2, m_in_w, xzb, nullptr, nullptr, 2048, 3072, 768, 768, 768, 3072,
      2048LL*768, 3072LL*768, 2048LL*3072, 0, 2, 0);
    conv_kernel<<<(4*1024*384 + 255)/256, 256, 0, stream>>>(xzb, xcb, m_conv_w, m_conv_b, 4, 1024, 1);
    G(xcb, m_xp_w, dblb, nullptr, nullptr, 2048, 80, 1536, 1536, 1536, 80,
      2048LL*1536, 80LL*1536, 2048LL*80, 0, 2, 0);
    G(dblb, m_dt_w, dtb, m_dt_b, nullptr, 2048, 1536, 48, 80, 48, 1536,
      2048LL*80, 1536LL*48, 2048LL*1536, 1536, 2, GF_BIAS | GF_SOFTPLUS);
    {
        const int NC = 8, CL = 128;                     // 8 chunks x 128 steps
        float* hend   = oe;                             // oe is dead here; reuse as scratch
        float* hstart = oe + (size_t)NC*4*DI*DS;
        float* sumdt  = oe + (size_t)2*NC*4*DI*DS;
        scan_p1<<<dim3(6, 4, NC), 256, 0, stream>>>(dtb, dblb, xcb, m_A_log, hend, sumdt, 1024, CL, 4, 1);
        scan_p2<<<(4*DI*DS)/256, 256, 0, stream>>>(hend, sumdt, m_A_log, hstart, NC, 4, 1);
        scan_p3<<<dim3(6, 4, NC), 256, 0, stream>>>(dtb, dblb, xcb, xzb, m_A_log, m_D, hstart, yb, 1024, CL, 4, 1);
    }
    G(yb, m_out_w, oe, nullptr, nullptr, 2048, 768, 1536, 1536, 1536, 768,
      2048LL*1536, 768LL*1536, 2048LL*768, 0, 2, 0);
    combine_kernel<<<(2*1024*192 + 255)/256, 256, 0, stream>>>(oe, X2, cbuf);

    // ---- 12 blocks ----
    for (int l = 0; l < NBK; ++l) {
        const int li = l + 2;
        ln_kernel<<<192, 256, 0, stream>>>(xbuf, xn, sn_g + (size_t)l*768, sn_b + (size_t)l*768, 768);
        G(xn, m_in_w + (size_t)li*3072*768, xzb, nullptr, nullptr,
          768, 3072, 768, 768, 768, 3072, 0,0,0,0, 1, 0);
        conv_kernel<<<(2*NQ*384 + 255)/256, 256, 0, stream>>>(
            xzb, xcb, m_conv_w + (size_t)li*DI*4, m_conv_b + (size_t)li*DI, 2, NQ, 8);
        G(xcb, m_xp_w + (size_t)li*80*1536, dblb, nullptr, nullptr,
          768, 80, 1536, 1536, 1536, 80, 0,0,0,0, 1, 0);
        G(dblb, m_dt_w + (size_t)li*1536*48, dtb, m_dt_b + (size_t)li*1536, nullptr,
          768, 1536, 48, 80, 48, 1536, 0,0,0,0, 1, GF_BIAS | GF_SOFTPLUS);
        {
            const int NC = 12, CL = 32;                 // 12 chunks x 32 steps
            const float* Ap = m_A_log + (size_t)li*DI*DS;
            float* hend   = oe;                         // oe (kv) consumed by last block's attn
            float* hstart = oe + (size_t)NC*2*DI*DS;
            float* sumdt  = oe + (size_t)2*NC*2*DI*DS;
            scan_p1<<<dim3(6, 2, NC), 256, 0, stream>>>(dtb, dblb, xcb, Ap, hend, sumdt, NQ, CL, 2, 8);
            scan_p2<<<(2*DI*DS)/256, 256, 0, stream>>>(hend, sumdt, Ap, hstart, NC, 2, 8);
            scan_p3<<<dim3(6, 2, NC), 256, 0, stream>>>(dtb, dblb, xcb, xzb, Ap, m_D + (size_t)li*DI,
                                                        hstart, yb, NQ, CL, 2, 8);
        }
        G(yb, m_out_w + (size_t)li*768*1536, x1, nullptr, xn,
          768, 768, 1536, 1536, 1536, 768, 0,0,0,0, 1, GF_ADDT);
        // attention
        G(x1, a_in_w + (size_t)l*2304*768, qb, a_in_b + (size_t)l*2304, nullptr,
          768, 768, 768, 768, 768, 768, 0,0,0,0, 1, GF_BIAS);
        G(cbuf, a_in_w + (size_t)l*2304*768 + 768*768, oe, a_in_b + (size_t)l*2304 + 768, nullptr,
          2048, 1536, 768, 768, 768, 1536, 0,0,0,0, 1, GF_BIAS);
        attn_kernel<<<2*NQ, 64, 0, stream>>>(qb, oe, ob);
        G(ob, a_out_w + (size_t)l*768*768, scb, a_out_b + (size_t)l*768, nullptr,
          768, 768, 768, 768, 768, 768, 0,0,0,0, 1, GF_BIAS);
        float* dst = (l == NBK - 1) ? out : xbuf;
        G(x1, cr_w + (size_t)l*768*1536, dst, cr_b + (size_t)l*768, nullptr,
          768, 768, 768, 768, 1536, 768, 0,0,0,0, 1, GF_BIAS);
        G(scb, cr_w + (size_t)l*768*1536 + 768, dst, nullptr, nullptr,
          768, 768, 768, 768, 1536, 768, 0,0,0,0, 1, GF_ACCUM);
    }
}

// Round 3
// 4638.257 us; speedup vs baseline: 2.4739x; 2.3053x over previous
//
#include <hip/hip_runtime.h>
#include <hip/hip_bf16.h>

// ---- model constants ----
#define DIMQ 768
#define D_IN 1024
#define NQ 384
#define NBK 12
#define BATCH 2
#define LSEQ 1024
#define DI 1536
#define DS 16
#define DTR 48
#define NH 16
#define HD 48

typedef __attribute__((ext_vector_type(8))) short short8;
typedef __attribute__((ext_vector_type(4))) float f32x4;

#define GF_BIAS 1
#define GF_SOFTPLUS 2
#define EPI_BIAS 1
#define EPI_ADDT 2

#define LOG2E 1.4426950408889634f

__device__ __forceinline__ unsigned short f2bf(float f) {
    unsigned int u = __builtin_bit_cast(unsigned int, f);
    u = (u + 0x7FFFu + ((u >> 16) & 1u)) >> 16;
    return (unsigned short)u;
}
__device__ __forceinline__ float bf2f(unsigned short h) {
    unsigned int u = ((unsigned int)h) << 16;
    return __builtin_bit_cast(float, u);
}

__device__ __forceinline__ void gload_lds16(const void* g, void* l) {
    __builtin_amdgcn_global_load_lds(
        (const __attribute__((address_space(1))) void*)g,
        (__attribute__((address_space(3))) void*)l, 16, 0, 0);
}

// ---------------------------------------------------------------------------
// Weight conversion: fp32 -> bf16 hi/lo planes, with zero padding.
// ---------------------------------------------------------------------------
struct WTab {
    const float* src[10];
    long long dstOff[10];
    long long ps[10];       // plane size (elems)
    int cum[10];            // cumulative end index
    int rows[10], cols[10], dcols[10];
    int n;
    int total;
};

__global__ void wconv_kernel(unsigned short* __restrict__ dst, WTab T)
{
    const int i = blockIdx.x * 256 + threadIdx.x;
    if (i >= T.total) return;
    int sI = 0;
    while (i >= T.cum[sI]) ++sI;
    const int e = i - (sI ? T.cum[sI - 1] : 0);
    const int dcols = T.dcols[sI];
    const int r = e / dcols;
    const int c = e - r * dcols;
    float v = 0.f;
    if (r < T.rows[sI] && c < T.cols[sI]) v = T.src[sI][(long long)r * T.cols[sI] + c];
    const unsigned short h = f2bf(v);
    const unsigned short l = f2bf(v - bf2f(h));
    dst[T.dstOff[sI] + e] = h;
    dst[T.dstOff[sI] + T.ps[sI] + e] = l;
}

// ---------------------------------------------------------------------------
// GEMM core: C[M,N] = A[M,K] (fp32, split in-kernel) * B[N,K]^T (bf16 hi/lo
// planes, staged via global_load_lds).  Tile 64x128, BK=32, 4 waves.
// M%64==0, N%128==0 (B planes padded), K%8==0.
// ---------------------------------------------------------------------------
__global__ __launch_bounds__(256, 4)
void gemm_direct(const float* __restrict__ Ag, const unsigned short* __restrict__ Bhl,
                 float* __restrict__ Cg, const float* __restrict__ biasg,
                 int M, int N, int K, int lda, int ldb, int ldc,
                 long long sA, long long sB, long long sC, long long sBias,
                 long long planeB, int flags)
{
    __shared__ __align__(16) unsigned short As[2][64][40];
    __shared__ __align__(16) unsigned short Bs[2][128][32];   // DMA region (contiguous)

    const int z = blockIdx.z;
    const float* A = Ag + (size_t)z * sA;
    const unsigned short* Bhi = Bhl + (size_t)z * sB;
    const unsigned short* Blo = Bhi + planeB;
    float* C = Cg + (size_t)z * sC;

    const int mBase = blockIdx.x * 64;
    const int nBase = blockIdx.y * 128;
    const int tid = threadIdx.x, lane = tid & 63, wave = tid >> 6;
    const int lm = lane & 15, lq = lane >> 4;
    const int wn = wave * 32;
    const int arow = tid >> 2, aq = tid & 3;
    const int brow = lane >> 2;
    const int bcol = (lane & 3) * 8;

    f32x4 acc[4][2] = {};
    const int ktiles = (K + 31) >> 5;

    for (int t = 0; t < ktiles; ++t) {
        const int kb = t * 32;
        // ---- B: 4 DMA chunks per wave (1 KiB each) ----
#pragma unroll
        for (int cc = 0; cc < 4; ++cc) {
            const int chunk = wave * 4 + cc;          // 0..15
            const int pl = chunk >> 3;                // 0=hi 1=lo
            const int r16 = chunk & 7;
            const unsigned short* bp = pl ? Blo : Bhi;
            const int n = nBase + r16 * 16 + brow;
            const unsigned short* g = bp + (size_t)n * ldb + kb + bcol;
            gload_lds16(g, &Bs[pl][r16 * 16][0]);
        }
        // ---- A: 8 elems/thread, fp32 -> hi/lo ----
        {
            const int gr = mBase + arow;
            const int col = kb + aq * 8;
            const float* src = A + (size_t)gr * lda + col;
            float v[8];
#pragma unroll
            for (int u = 0; u < 2; ++u) {
                float4 t4 = make_float4(0.f, 0.f, 0.f, 0.f);
                if (col + u * 4 < K) t4 = *(const float4*)(src + u * 4);
                v[u*4+0]=t4.x; v[u*4+1]=t4.y; v[u*4+2]=t4.z; v[u*4+3]=t4.w;
            }
            short8 ph, plv;
#pragma unroll
            for (int j = 0; j < 8; ++j) {
                unsigned short h = f2bf(v[j]);
                ph[j] = (short)h;
                plv[j] = (short)f2bf(v[j] - bf2f(h));
            }
            *(short8*)&As[0][arow][aq * 8] = ph;
            *(short8*)&As[1][arow][aq * 8] = plv;
        }
        __syncthreads();
        // ---- compute ----
        short8 ah[4], al[4], bh[2], bl[2];
#pragma unroll
        for (int i = 0; i < 4; ++i) {
            ah[i] = *(const short8*)&As[0][16*i + lm][lq * 8];
            al[i] = *(const short8*)&As[1][16*i + lm][lq * 8];
        }
#pragma unroll
        for (int j = 0; j < 2; ++j) {
            bh[j] = *(const short8*)&Bs[0][wn + 16*j + lm][lq * 8];
            bl[j] = *(const short8*)&Bs[1][wn + 16*j + lm][lq * 8];
        }
#pragma unroll
        for (int i = 0; i < 4; ++i)
#pragma unroll
            for (int j = 0; j < 2; ++j) {
                acc[i][j] = __builtin_amdgcn_mfma_f32_16x16x32_bf16(ah[i], bh[j], acc[i][j], 0, 0, 0);
                acc[i][j] = __builtin_amdgcn_mfma_f32_16x16x32_bf16(ah[i], bl[j], acc[i][j], 0, 0, 0);
                acc[i][j] = __builtin_amdgcn_mfma_f32_16x16x32_bf16(al[i], bh[j], acc[i][j], 0, 0, 0);
            }
        __syncthreads();
    }

#pragma unroll
    for (int i = 0; i < 4; ++i)
#pragma unroll
        for (int j = 0; j < 2; ++j)
#pragma unroll
            for (int r = 0; r < 4; ++r) {
                const int m = mBase + i*16 + lq*4 + r;
                const int n = nBase + wn + j*16 + lm;
                float v = acc[i][j][r];
                if (flags & GF_BIAS)     v += biasg[(size_t)z * sBias + n];
                if (flags & GF_SOFTPLUS) v = (v > 20.f) ? v : log1pf(expf(v));
                C[(size_t)m * ldc + n] = v;
            }
}

// Split-K variant: grid.z = Z*S; writes partials Cp[(z*S+s)][M][ldP].
__global__ __launch_bounds__(256, 4)
void gemm_splitk(const float* __restrict__ Ag, const unsigned short* __restrict__ Bhl,
                 float* __restrict__ Cp,
                 int M, int kLen, int S, int lda, int ldb, int ldP,
                 long long sA, long long sB, long long planeB)
{
    __shared__ __align__(16) unsigned short As[2][64][40];
    __shared__ __align__(16) unsigned short Bs[2][128][32];

    const int bz = blockIdx.z;
    const int s = bz % S, z = bz / S;
    const int kOff = s * kLen;
    const float* A = Ag + (size_t)z * sA;
    const unsigned short* Bhi = Bhl + (size_t)z * sB;
    const unsigned short* Blo = Bhi + planeB;

    const int mBase = blockIdx.x * 64;
    const int nBase = blockIdx.y * 128;
    const int tid = threadIdx.x, lane = tid & 63, wave = tid >> 6;
    const int lm = lane & 15, lq = lane >> 4;
    const int wn = wave * 32;
    const int arow = tid >> 2, aq = tid & 3;
    const int brow = lane >> 2;
    const int bcol = (lane & 3) * 8;

    f32x4 acc[4][2] = {};
    const int ktiles = kLen >> 5;

    for (int t = 0; t < ktiles; ++t) {
        const int kb = kOff + t * 32;
#pragma unroll
        for (int cc = 0; cc < 4; ++cc) {
            const int chunk = wave * 4 + cc;
            const int pl = chunk >> 3;
            const int r16 = chunk & 7;
            const unsigned short* bp = pl ? Blo : Bhi;
            const int n = nBase + r16 * 16 + brow;
            gload_lds16(bp + (size_t)n * ldb + kb + bcol, &Bs[pl][r16 * 16][0]);
        }
        {
            const int gr = mBase + arow;
            const float* src = A + (size_t)gr * lda + kb + aq * 8;
            float v[8];
#pragma unroll
            for (int u = 0; u < 2; ++u) {
                const float4 t4 = *(const float4*)(src + u * 4);
                v[u*4+0]=t4.x; v[u*4+1]=t4.y; v[u*4+2]=t4.z; v[u*4+3]=t4.w;
            }
            short8 ph, plv;
#pragma unroll
            for (int j = 0; j < 8; ++j) {
                unsigned short h = f2bf(v[j]);
                ph[j] = (short)h;
                plv[j] = (short)f2bf(v[j] - bf2f(h));
            }
            *(short8*)&As[0][arow][aq * 8] = ph;
            *(short8*)&As[1][arow][aq * 8] = plv;
        }
        __syncthreads();
        short8 ah[4], al[4], bh[2], bl[2];
#pragma unroll
        for (int i = 0; i < 4; ++i) {
            ah[i] = *(const short8*)&As[0][16*i + lm][lq * 8];
            al[i] = *(const short8*)&As[1][16*i + lm][lq * 8];
        }
#pragma unroll
        for (int j = 0; j < 2; ++j) {
            bh[j] = *(const short8*)&Bs[0][wn + 16*j + lm][lq * 8];
            bl[j] = *(const short8*)&Bs[1][wn + 16*j + lm][lq * 8];
        }
#pragma unroll
        for (int i = 0; i < 4; ++i)
#pragma unroll
            for (int j = 0; j < 2; ++j) {
                acc[i][j] = __builtin_amdgcn_mfma_f32_16x16x32_bf16(ah[i], bh[j], acc[i][j], 0, 0, 0);
                acc[i][j] = __builtin_amdgcn_mfma_f32_16x16x32_bf16(ah[i], bl[j], acc[i][j], 0, 0, 0);
                acc[i][j] = __builtin_amdgcn_mfma_f32_16x16x32_bf16(al[i], bh[j], acc[i][j], 0, 0, 0);
            }
        __syncthreads();
    }

    float* Cb = Cp + (size_t)bz * M * ldP;
#pragma unroll
    for (int i = 0; i < 4; ++i)
#pragma unroll
        for (int j = 0; j < 2; ++j)
#pragma unroll
            for (int r = 0; r < 4; ++r) {
                const int m = mBase + i*16 + lq*4 + r;
                const int n = nBase + wn + j*16 + lm;
                Cb[(size_t)m * ldP + n] = acc[i][j][r];
            }
}

// Reduce partials + bias/residual, write fp32 out.
__global__ void epi_kernel(const float* __restrict__ Cp, float* __restrict__ outF,
                           const float* __restrict__ bias, const float* __restrict__ addT,
                           int Z, int S, int M, int N, int ldP, int ldOut,
                           long long sOutZ, long long sBiasZ, int ldAdd, int flags)
{
    const int n4 = N >> 2;
    const int idx = blockIdx.x * 256 + threadIdx.x;
    if (idx >= Z * M * n4) return;
    const int c4 = idx % n4;
    const int rem = idx / n4;
    const int m = rem % M;
    const int z = rem / M;
    const int n = c4 * 4;
    const float* base = Cp + ((size_t)z * S * M + m) * ldP + n;
    float4 v = *(const float4*)base;
    for (int s = 1; s < S; ++s) {
        const float4 u = *(const float4*)(base + (size_t)s * M * ldP);
        v.x += u.x; v.y += u.y; v.z += u.z; v.w += u.w;
    }
    if (flags & EPI_BIAS) {
        const float4 b4 = *(const float4*)(bias + (size_t)z * sBiasZ + n);
        v.x += b4.x; v.y += b4.y; v.z += b4.z; v.w += b4.w;
    }
    if (flags & EPI_ADDT) {
        const float4 a4 = *(const float4*)(addT + (size_t)m * ldAdd + n);
        v.x += a4.x; v.y += a4.y; v.z += a4.z; v.w += a4.w;
    }
    *(float4*)(outF + (size_t)z * sOutZ + (size_t)m * ldOut + n) = v;
}

// ---------------------------------------------------------------------------
// LayerNorm over last dim 768. One wave per row.
// ---------------------------------------------------------------------------
__global__ void ln_kernel(const float* __restrict__ in, float* __restrict__ out,
                          const float* __restrict__ g, const float* __restrict__ b, int rows)
{
    const int row = blockIdx.x * 4 + (threadIdx.x >> 6);
    const int lane = threadIdx.x & 63;
    if (row >= rows) return;
    const float* p = in + (size_t)row * DIMQ;
    float v[12], s = 0.f, s2 = 0.f;
#pragma unroll
    for (int j = 0; j < 12; ++j) {
        v[j] = p[j*64 + lane];
        s += v[j];
        s2 += v[j]*v[j];
    }
#pragma unroll
    for (int o = 32; o; o >>= 1) { s += __shfl_xor(s, o); s2 += __shfl_xor(s2, o); }
    const float mean = s * (1.f/768.f);
    const float var  = s2 * (1.f/768.f) - mean*mean;
    const float inv  = rsqrtf(var + 1e-5f);
    float* q = out + (size_t)row * DIMQ;
#pragma unroll
    for (int j = 0; j < 12; ++j) {
        const int c = j*64 + lane;
        q[c] = (v[j] - mean) * inv * g[c] + b[c];
    }
}

// ---------------------------------------------------------------------------
// Depthwise causal conv1d (DC=4) + silu.
// ---------------------------------------------------------------------------
__global__ void conv_kernel(const float* __restrict__ xz, float* __restrict__ xc,
                            const float* __restrict__ cw, const float* __restrict__ cb,
                            int Bn, int L, int instShift)
{
    const int idx = blockIdx.x * 256 + threadIdx.x;
    const int total = Bn * L * (DI/4);
    if (idx >= total) return;
    const int d4 = idx % (DI/4);
    const int t  = (idx / (DI/4)) % L;
    const int b  = idx / (L * (DI/4));
    const int inst = b >> instShift;
    const int d = d4 * 4;
    const float* base = xz + (size_t)(b * L) * 3072 + d;
    const float4 w0 = *(const float4*)(cw + (size_t)(inst*DI + d + 0) * 4);
    const float4 w1 = *(const float4*)(cw + (size_t)(inst*DI + d + 1) * 4);
    const float4 w2 = *(const float4*)(cw + (size_t)(inst*DI + d + 2) * 4);
    const float4 w3 = *(const float4*)(cw + (size_t)(inst*DI + d + 3) * 4);
    float4 acc = *(const float4*)(cb + (size_t)inst*DI + d);
    float4 xv[4];
#pragma unroll
    for (int j = 0; j < 4; ++j) {
        const int tt = t - 3 + j;
        xv[j] = (tt >= 0) ? *(const float4*)(base + (size_t)tt * 3072) : make_float4(0,0,0,0);
    }
    acc.x += xv[0].x*w0.x + xv[1].x*w0.y + xv[2].x*w0.z + xv[3].x*w0.w;
    acc.y += xv[0].y*w1.x + xv[1].y*w1.y + xv[2].y*w1.z + xv[3].y*w1.w;
    acc.z += xv[0].z*w2.x + xv[1].z*w2.y + xv[2].z*w2.z + xv[3].z*w2.w;
    acc.w += xv[0].w*w3.x + xv[1].w*w3.y + xv[2].w*w3.z + xv[3].w*w3.w;
    float4 o;
    o.x = acc.x / (1.f + expf(-acc.x));
    o.y = acc.y / (1.f + expf(-acc.y));
    o.z = acc.z / (1.f + expf(-acc.z));
    o.w = acc.w / (1.f + expf(-acc.w));
    *(float4*)(xc + (size_t)(b * L + t) * DI + d) = o;
}

// ---------------------------------------------------------------------------
// Chunked selective scan (3 passes), unchanged from round 2.
// ---------------------------------------------------------------------------
__global__ __launch_bounds__(256)
void scan_p1(const float* __restrict__ dt, const float* __restrict__ dbl,
             const float* __restrict__ xc, const float* __restrict__ A_log,
             float* __restrict__ hend, float* __restrict__ sumdt,
             int L, int CL, int Bn, int instShift)
{
    const int d = blockIdx.x * 256 + threadIdx.x;
    const int b = blockIdx.y;
    const int c = blockIdx.z;
    const int inst = b >> instShift;
    const float* ap = A_log + ((size_t)inst * DI + d) * DS;
    float A2[16];
#pragma unroll
    for (int s = 0; s < 16; ++s) A2[s] = -expf(ap[s]) * LOG2E;
    float h[16] = {};
    float sd = 0.f;
    const int t0 = c * CL;
    const size_t rowbase = (size_t)b * L;
    for (int t = t0; t < t0 + CL; ++t) {
        const size_t row = rowbase + t;
        const float dtv = dt[row * DI + d];
        const float xcv = xc[row * DI + d];
        float Bv[16];
        *(float4*)(Bv + 0)  = *(const float4*)(dbl + row * 80 + 48);
        *(float4*)(Bv + 4)  = *(const float4*)(dbl + row * 80 + 52);
        *(float4*)(Bv + 8)  = *(const float4*)(dbl + row * 80 + 56);
        *(float4*)(Bv + 12) = *(const float4*)(dbl + row * 80 + 60);
        sd += dtv;
        const float bx = dtv * xcv;
#pragma unroll
        for (int s = 0; s < 16; ++s)
            h[s] = exp2f(dtv * A2[s]) * h[s] + bx * Bv[s];
    }
    float* hp = hend + (((size_t)c * Bn + b) * DI + d) * DS;
#pragma unroll
    for (int s = 0; s < 16; s += 4)
        *(float4*)(hp + s) = make_float4(h[s], h[s+1], h[s+2], h[s+3]);
    sumdt[((size_t)c * Bn + b) * DI + d] = sd;
}

__global__ void scan_p2(const float* __restrict__ hend, const float* __restrict__ sumdt,
                        const float* __restrict__ A_log, float* __restrict__ hstart,
                        int NC, int Bn, int instShift)
{
    const int gid = blockIdx.x * 256 + threadIdx.x;
    const int s = gid & 15;
    const int rem = gid >> 4;
    const int d = rem % DI;
    const int b = rem / DI;
    const int inst = b >> instShift;
    const float A2 = -expf(A_log[((size_t)inst * DI + d) * DS + s]) * LOG2E;
    float carry = 0.f;
    for (int c = 0; c < NC; ++c) {
        const size_t off = (((size_t)c * Bn + b) * DI + d) * DS + s;
        hstart[off] = carry;
        carry = exp2f(A2 * sumdt[((size_t)c * Bn + b) * DI + d]) * carry + hend[off];
    }
}

__global__ __launch_bounds__(256)
void scan_p3(const float* __restrict__ dt, const float* __restrict__ dbl,
             const float* __restrict__ xc, const float* __restrict__ xz,
             const float* __restrict__ A_log, const float* __restrict__ Dp,
             const float* __restrict__ hstart, float* __restrict__ y,
             int L, int CL, int Bn, int instShift)
{
    const int d = blockIdx.x * 256 + threadIdx.x;
    const int b = blockIdx.y;
    const int c = blockIdx.z;
    const int inst = b >> instShift;
    const float* ap = A_log + ((size_t)inst * DI + d) * DS;
    float A2[16];
#pragma unroll
    for (int s = 0; s < 16; ++s) A2[s] = -expf(ap[s]) * LOG2E;
    const float Dd = Dp[(size_t)inst * DI + d];
    float h[16];
    const float* hp = hstart + (((size_t)c * Bn + b) * DI + d) * DS;
#pragma unroll
    for (int s = 0; s < 16; s += 4) {
        const float4 t4 = *(const float4*)(hp + s);
        h[s] = t4.x; h[s+1] = t4.y; h[s+2] = t4.z; h[s+3] = t4.w;
    }
    const int t0 = c * CL;
    const size_t rowbase = (size_t)b * L;
    for (int t = t0; t < t0 + CL; ++t) {
        const size_t row = rowbase + t;
        const float dtv = dt[row * DI + d];
        const float xcv = xc[row * DI + d];
        const float zv  = xz[row * 3072 + DI + d];
        float Bv[16], Cv[16];
        *(float4*)(Bv + 0)  = *(const float4*)(dbl + row * 80 + 48);
        *(float4*)(Bv + 4)  = *(const float4*)(dbl + row * 80 + 52);
        *(float4*)(Bv + 8)  = *(const float4*)(dbl + row * 80 + 56);
        *(float4*)(Bv + 12) = *(const float4*)(dbl + row * 80 + 60);
        *(float4*)(Cv + 0)  = *(const float4*)(dbl + row * 80 + 64);
        *(float4*)(Cv + 4)  = *(const float4*)(dbl + row * 80 + 68);
        *(float4*)(Cv + 8)  = *(const float4*)(dbl + row * 80 + 72);
        *(float4*)(Cv + 12) = *(const float4*)(dbl + row * 80 + 76);
        const float bx = dtv * xcv;
#pragma unroll
        for (int s = 0; s < 16; ++s)
            h[s] = exp2f(dtv * A2[s]) * h[s] + bx * Bv[s];
        float p0 = 0.f, p1 = 0.f, p2 = 0.f, p3 = 0.f;
#pragma unroll
        for (int s = 0; s < 4; ++s) {
            p0 += h[s]      * Cv[s];
            p1 += h[s + 4]  * Cv[s + 4];
            p2 += h[s + 8]  * Cv[s + 8];
            p3 += h[s + 12] * Cv[s + 12];
        }
        const float p = (p0 + p1) + (p2 + p3);
        y[row * DI + d] = (p + Dd * xcv) * (zv / (1.f + expf(-zv)));
    }
}

// ---------------------------------------------------------------------------
// Local-window cross attention (2-3 keys/query).
// ---------------------------------------------------------------------------
__global__ void attn_kernel(const float* __restrict__ q, const float* __restrict__ kv,
                            float* __restrict__ o)
{
    const int bi = blockIdx.x;
    const int b = bi / NQ, i = bi % NQ;
    const int tid = threadIdx.x;
    const int h = tid >> 2, r = tid & 3;
    int start, len;
    if (i < 256) { start = 3*i; len = 3; } else { start = 2*i + 256; len = 2; }
    const float* qp = q + (size_t)bi * DIMQ + h*48 + r*12;
    float qv[12];
#pragma unroll
    for (int u = 0; u < 12; ++u) qv[u] = qp[u];
    float s[3] = {-1e30f, -1e30f, -1e30f};
    for (int j = 0; j < len; ++j) {
        const float* kp = kv + (size_t)(b*LSEQ + start + j) * 1536 + h*48 + r*12;
        float p = 0.f;
#pragma unroll
        for (int u = 0; u < 12; ++u) p += qv[u] * kp[u];
        p += __shfl_xor(p, 1);
        p += __shfl_xor(p, 2);
        s[j] = p * 0.14433756729740644f;
    }
    const float mx = fmaxf(s[0], fmaxf(s[1], s[2]));
    float e[3];
    e[0] = expf(s[0]-mx); e[1] = expf(s[1]-mx); e[2] = expf(s[2]-mx);
    const float inv = 1.f / (e[0] + e[1] + e[2]);
    float ov[12] = {};
    for (int j = 0; j < len; ++j) {
        const float w = e[j] * inv;
        const float* vp = kv + (size_t)(b*LSEQ + start + j) * 1536 + 768 + h*48 + r*12;
#pragma unroll
        for (int u = 0; u < 12; ++u) ov[u] += w * vp[u];
    }
    float* op = o + (size_t)bi * DIMQ + h*48 + r*12;
#pragma unroll
    for (int u = 0; u < 12; ++u) op[u] = ov[u];
}

// ---------------------------------------------------------------------------
// small utility kernels
// ---------------------------------------------------------------------------
__global__ void flip_kernel(float* __restrict__ X2)
{
    const int idx = blockIdx.x * 256 + threadIdx.x;
    if (idx >= 2*1024*192) return;
    const int d4 = idx % 192;
    const int t  = (idx / 192) % 1024;
    const int b  = idx / (192 * 1024);
    const size_t dst = ((size_t)((2+b)*1024 + t)) * DIMQ + d4*4;
    const size_t src = ((size_t)(b*1024 + (1023 - t))) * DIMQ + d4*4;
    *(float4*)(X2 + dst) = *(const float4*)(X2 + src);
}

__global__ void combine_kernel(const float* __restrict__ oe, const float* __restrict__ feats,
                               float* __restrict__ c)
{
    const int idx = blockIdx.x * 256 + threadIdx.x;
    if (idx >= 2*1024*192) return;
    const int d4 = idx % 192;
    const int t  = (idx / 192) % 1024;
    const int b  = idx / (192 * 1024);
    const size_t fw = ((size_t)(b*1024 + t)) * DIMQ + d4*4;
    const size_t bw = ((size_t)((2+b)*1024 + (1023 - t))) * DIMQ + d4*4;
    const float4 a = *(const float4*)(oe + fw);
    const float4 bb = *(const float4*)(oe + bw);
    const float4 f = *(const float4*)(feats + fw);
    float4 o;
    o.x = a.x + bb.x + f.x; o.y = a.y + bb.y + f.y;
    o.z = a.z + bb.z + f.z; o.w = a.w + bb.w + f.w;
    *(float4*)(c + fw) = o;
}

__global__ void qinit_kernel(float* __restrict__ x, const float* __restrict__ queries)
{
    const int idx = blockIdx.x * 256 + threadIdx.x;
    if (idx >= 2*NQ*192) return;
    const int d4 = idx % 192;
    const int i  = (idx / 192) % NQ;
    *(float4*)(x + (size_t)idx * 4) = *(const float4*)(queries + ((size_t)i * DIMQ + d4*4));
}

// ---------------------------------------------------------------------------
extern "C" void kernel_launch(void* const* d_in, const int* in_sizes, int n_in,
                              void* d_out, int out_size, void* d_ws, size_t ws_size,
                              hipStream_t stream) {
    const float* img_emb  = (const float*)d_in[0];
    const float* queries  = (const float*)d_in[1];
    const float* vis_w    = (const float*)d_in[2];
    const float* vis_b    = (const float*)d_in[3];
    const float* lnv_g    = (const float*)d_in[4];
    const float* lnv_b    = (const float*)d_in[5];
    const float* m_in_w   = (const float*)d_in[6];
    const float* m_conv_w = (const float*)d_in[7];
    const float* m_conv_b = (const float*)d_in[8];
    const float* m_xp_w   = (const float*)d_in[9];
    const float* m_dt_w   = (const float*)d_in[10];
    const float* m_dt_b   = (const float*)d_in[11];
    const float* m_A_log  = (const float*)d_in[12];
    const float* m_D      = (const float*)d_in[13];
    const float* m_out_w  = (const float*)d_in[14];
    const float* sn_g     = (const float*)d_in[15];
    const float* sn_b     = (const float*)d_in[16];
    const float* a_in_w   = (const float*)d_in[17];
    const float* a_in_b   = (const float*)d_in[18];
    const float* a_out_w  = (const float*)d_in[19];
    const float* a_out_b  = (const float*)d_in[20];
    const float* cr_w     = (const float*)d_in[21];
    const float* cr_b     = (const float*)d_in[22];
    float* out = (float*)d_out;

    float* ws = (float*)d_ws;
    float* X2   = ws; ws += (size_t)4096*768;
    float* xzb  = ws; ws += (size_t)4096*3072;
    float* xcb  = ws; ws += (size_t)4096*1536;
    float* dblb = ws; ws += (size_t)4096*80;
    float* dtb  = ws; ws += (size_t)4096*1536;
    float* yb   = ws; ws += (size_t)4096*1536;
    float* oe   = ws; ws += (size_t)4096*768;   // vis tmp / enc out / scan scratch / kv
    float* cbuf = ws; ws += (size_t)2048*768;
    float* xbuf = ws; ws += (size_t)768*768;
    float* xn   = ws; ws += (size_t)768*768;
    float* x1s  = ws; ws += (size_t)768*1536;   // [x1 | score] fp32
    float* qb   = ws; ws += (size_t)768*768;
    float* ob   = ws; ws += (size_t)768*768;
    float* Cp   = ws; ws += (size_t)2359296;    // split-K partials
    unsigned short* wenc = (unsigned short*)ws; ws += (size_t)16908288/2;
    unsigned short* wlay = (unsigned short*)ws; ws += (size_t)14745600/2;

    // weight plane sizes (bf16 elems)
    const long long P_VIS = 768LL*1024;
    const long long P_IN  = 3072LL*768;
    const long long P_XP  = 128LL*1536;
    const long long P_DT  = 1536LL*64;
    const long long P_OUT = 768LL*1536;
    const long long P_AIN = 2304LL*768;
    const long long P_AOUT= 768LL*768;
    const long long P_CR  = 768LL*1536;
    // encoder buffer layout
    const long long off_vis   = 0;
    const long long off_encIn = 2*P_VIS;
    const long long off_encXp = off_encIn + 4*P_IN;
    const long long off_encDt = off_encXp + 4*P_XP;
    const long long off_encOut= off_encDt + 4*P_DT;
    // layer buffer layout
    const long long off_in  = 0;
    const long long off_xp  = 2*P_IN;
    const long long off_dt  = off_xp + 2*P_XP;
    const long long off_out = off_dt + 2*P_DT;
    const long long off_aIn = off_out + 2*P_OUT;
    const long long off_aOut= off_aIn + 2*P_AIN;
    const long long off_cr  = off_aOut + 2*P_AOUT;

    auto addSeg = [](WTab& T, const float* src, int rows, int cols, int drows, int dcols,
                     long long dstOff) {
        const int k = T.n;
        T.src[k] = src; T.rows[k] = rows; T.cols[k] = cols; T.dcols[k] = dcols;
        T.ps[k] = (long long)drows * dcols;
        T.dstOff[k] = dstOff;
        T.total += drows * dcols;
        T.cum[k] = T.total;
        T.n = k + 1;
    };

    auto GD = [&](const float* A, const unsigned short* Bhl, long long planeB,
                  float* C, const float* bias,
                  int M, int N, int K, int lda, int ldb, int ldc,
                  long long sA, long long sB, long long sC, long long sBias,
                  int Z, int flags) {
        dim3 grid(M/64, N/128, Z);
        gemm_direct<<<grid, 256, 0, stream>>>(A, Bhl, C, bias, M, N, K, lda, ldb, ldc,
                                              sA, sB, sC, sBias, planeB, flags);
    };
    auto GS = [&](const float* A, const unsigned short* Bhl, long long planeB,
                  int M, int Ntile, int kLen, int S, int lda, int ldb, int ldP,
                  long long sA, long long sB, int Z) {
        dim3 grid(M/64, Ntile/128, Z*S);
        gemm_splitk<<<grid, 256, 0, stream>>>(A, Bhl, Cp, M, kLen, S, lda, ldb, ldP,
                                              sA, sB, planeB);
    };
    auto EPI = [&](float* outF, const float* bias, const float* addT,
                   int Z, int S, int M, int N, int ldP, int ldOut,
                   long long sOutZ, long long sBiasZ, int ldAdd, int flags) {
        const int total = Z * M * (N/4);
        epi_kernel<<<(total+255)/256, 256, 0, stream>>>(Cp, outF, bias, addT, Z, S, M, N,
                                                        ldP, ldOut, sOutZ, sBiasZ, ldAdd, flags);
    };

    // ==== encoder weight conversion ====
    {
        WTab T = {}; T.n = 0; T.total = 0;
        addSeg(T, vis_w, 768, 1024, 768, 1024, off_vis);
        addSeg(T, m_in_w,               3072, 768, 3072, 768, off_encIn);
        addSeg(T, m_in_w + 3072*768,    3072, 768, 3072, 768, off_encIn + 2*P_IN);
        addSeg(T, m_xp_w,               80, 1536, 128, 1536, off_encXp);
        addSeg(T, m_xp_w + 80*1536,     80, 1536, 128, 1536, off_encXp + 2*P_XP);
        addSeg(T, m_dt_w,               1536, 48, 1536, 64, off_encDt);
        addSeg(T, m_dt_w + 1536*48,     1536, 48, 1536, 64, off_encDt + 2*P_DT);
        addSeg(T, m_out_w,              768, 1536, 768, 1536, off_encOut);
        addSeg(T, m_out_w + 768*1536,   768, 1536, 768, 1536, off_encOut + 2*P_OUT);
        wconv_kernel<<<(T.total+255)/256, 256, 0, stream>>>(wenc, T);
    }

    // ==== vision proj + LN + stacked feats ====
    GD(img_emb, wenc + off_vis, P_VIS, oe, vis_b,
       2048, 768, 1024, 1024, 1024, 768, 0,0,0,0, 1, GF_BIAS);
    ln_kernel<<<512, 256, 0, stream>>>(oe, X2, lnv_g, lnv_b, 2048);
    flip_kernel<<<(2*1024*192 + 255)/256, 256, 0, stream>>>(X2);
    qinit_kernel<<<(2*NQ*192 + 255)/256, 256, 0, stream>>>(xbuf, queries);

    // ==== encoder mambas (fwd + bwd via Z=2) ====
    GD(X2, wenc + off_encIn, P_IN, xzb, nullptr,
       2048, 3072, 768, 768, 768, 3072, 2048LL*768, 2*P_IN, 2048LL*3072, 0, 2, 0);
    conv_kernel<<<(4*1024*384 + 255)/256, 256, 0, stream>>>(xzb, xcb, m_conv_w, m_conv_b, 4, 1024, 1);
    GS(xcb, wenc + off_encXp, P_XP, 2048, 128, 384, 4, 1536, 1536, 128,
       2048LL*1536, 2*P_XP, 2);
    EPI(dblb, nullptr, nullptr, 2, 4, 2048, 80, 128, 80, 2048LL*80, 0, 0, 0);
    GD(dblb, wenc + off_encDt, P_DT, dtb, m_dt_b,
       2048, 1536, 48, 80, 64, 1536, 2048LL*80, 2*P_DT, 2048LL*1536, 1536, 2,
       GF_BIAS | GF_SOFTPLUS);
    {
        const int NC = 8, CL = 128;
        float* hend   = oe;
        float* hstart = oe + (size_t)NC*4*DI*DS;
        float* sumdt  = oe + (size_t)2*NC*4*DI*DS;
        scan_p1<<<dim3(6, 4, NC), 256, 0, stream>>>(dtb, dblb, xcb, m_A_log, hend, sumdt, 1024, CL, 4, 1);
        scan_p2<<<(4*DI*DS)/256, 256, 0, stream>>>(hend, sumdt, m_A_log, hstart, NC, 4, 1);
        scan_p3<<<dim3(6, 4, NC), 256, 0, stream>>>(dtb, dblb, xcb, xzb, m_A_log, m_D, hstart, yb, 1024, CL, 4, 1);
    }
    GD(yb, wenc + off_encOut, P_OUT, oe, nullptr,
       2048, 768, 1536, 1536, 1536, 768, 2048LL*1536, 2*P_OUT, 2048LL*768, 0, 2, 0);
    combine_kernel<<<(2*1024*192 + 255)/256, 256, 0, stream>>>(oe, X2, cbuf);

    // ==== 12 blocks ====
    for (int l = 0; l < NBK; ++l) {
        const int li = l + 2;
        // convert this layer's weights
        {
            WTab T = {}; T.n = 0; T.total = 0;
            addSeg(T, m_in_w + (size_t)li*3072*768, 3072, 768, 3072, 768, off_in);
            addSeg(T, m_xp_w + (size_t)li*80*1536,  80, 1536, 128, 1536, off_xp);
            addSeg(T, m_dt_w + (size_t)li*1536*48,  1536, 48, 1536, 64, off_dt);
            addSeg(T, m_out_w + (size_t)li*768*1536, 768, 1536, 768, 1536, off_out);
            addSeg(T, a_in_w + (size_t)l*2304*768,  2304, 768, 2304, 768, off_aIn);
            addSeg(T, a_out_w + (size_t)l*768*768,  768, 768, 768, 768, off_aOut);
            addSeg(T, cr_w + (size_t)l*768*1536,    768, 1536, 768, 1536, off_cr);
            wconv_kernel<<<(T.total+255)/256, 256, 0, stream>>>(wlay, T);
        }
        ln_kernel<<<192, 256, 0, stream>>>(xbuf, xn, sn_g + (size_t)l*768, sn_b + (size_t)l*768, 768);
        // in-proj
        GD(xn, wlay + off_in, P_IN, xzb, nullptr,
           768, 3072, 768, 768, 768, 3072, 0,0,0,0, 1, 0);
        conv_kernel<<<(2*NQ*384 + 255)/256, 256, 0, stream>>>(
            xzb, xcb, m_conv_w + (size_t)li*DI*4, m_conv_b + (size_t)li*DI, 2, NQ, 8);
        // x-proj (split-K 16)
        GS(xcb, wlay + off_xp, P_XP, 768, 128, 96, 16, 1536, 1536, 128, 0, 0, 1);
        EPI(dblb, nullptr, nullptr, 1, 16, 768, 80, 128, 80, 0, 0, 0, 0);
        // dt-proj
        GD(dblb, wlay + off_dt, P_DT, dtb, m_dt_b + (size_t)li*1536,
           768, 1536, 48, 80, 64, 1536, 0,0,0,0, 1, GF_BIAS | GF_SOFTPLUS);
        // scan
        {
            const int NC = 12, CL = 32;
            const float* Ap = m_A_log + (size_t)li*DI*DS;
            float* hend   = oe;
            float* hstart = oe + (size_t)NC*2*DI*DS;
            float* sumdt  = oe + (size_t)2*NC*2*DI*DS;
            scan_p1<<<dim3(6, 2, NC), 256, 0, stream>>>(dtb, dblb, xcb, Ap, hend, sumdt, NQ, CL, 2, 8);
            scan_p2<<<(2*DI*DS)/256, 256, 0, stream>>>(hend, sumdt, Ap, hstart, NC, 2, 8);
            scan_p3<<<dim3(6, 2, NC), 256, 0, stream>>>(dtb, dblb, xcb, xzb, Ap, m_D + (size_t)li*DI,
                                                        hstart, yb, NQ, CL, 2, 8);
        }
        // out-proj (split-K 4) + residual -> x1s[:, :768]
        GS(yb, wlay + off_out, P_OUT, 768, 768, 384, 4, 1536, 1536, 768, 0, 0, 1);
        EPI(x1s, nullptr, xn, 1, 4, 768, 768, 768, 1536, 0, 0, 768, EPI_ADDT);
        // q-proj (split-K 4)
        GS(x1s, wlay + off_aIn, P_AIN, 768, 768, 192, 4, 1536, 768, 768, 0, 0, 1);
        EPI(qb, a_in_b + (size_t)l*2304, nullptr, 1, 4, 768, 768, 768, 768, 0, 0, 0, EPI_BIAS);
        // kv-proj (direct)
        GD(cbuf, wlay + off_aIn + 768LL*768, P_AIN, oe, a_in_b + (size_t)l*2304 + 768,
           2048, 1536, 768, 768, 768, 1536, 0,0,0,0, 1, GF_BIAS);
        attn_kernel<<<2*NQ, 64, 0, stream>>>(qb, oe, ob);
        // attn out-proj (split-K 4) -> x1s[:, 768:]
        GS(ob, wlay + off_aOut, P_AOUT, 768, 768, 192, 4, 768, 768, 768, 0, 0, 1);
        EPI(x1s + 768, a_out_b + (size_t)l*768, nullptr, 1, 4, 768, 768, 768, 1536, 0, 0, 0, EPI_BIAS);
        // cross proj: [x1|score] @ cr_w^T  (split-K 4)
        float* dst = (l == NBK - 1) ? out : xbuf;
        GS(x1s, wlay + off_cr, P_CR, 768, 768, 384, 4, 1536, 1536, 768, 0, 0, 1);
        EPI(dst, cr_b + (size_t)l*768, nullptr, 1, 4, 768, 768, 768, 768, 0, 0, 0, EPI_BIAS);
    }
}

// Round 4
// 4503.683 us; speedup vs baseline: 2.5478x; 1.0299x over previous
//
#include <hip/hip_runtime.h>
#include <hip/hip_bf16.h>

// ---- model constants ----
#define DIMQ 768
#define D_IN 1024
#define NQ 384
#define NBK 12
#define BATCH 2
#define LSEQ 1024
#define DI 1536
#define DS 16
#define DTR 48
#define NH 16
#define HD 48

typedef __attribute__((ext_vector_type(8))) short short8;
typedef __attribute__((ext_vector_type(4))) float f32x4;

#define GF_BIAS 1
#define GF_SOFTPLUS 2
#define EPI_BIAS 1
#define EPI_ADDT 2

#define LOG2E 1.4426950408889634f

__device__ __forceinline__ unsigned short f2bf(float f) {
    unsigned int u = __builtin_bit_cast(unsigned int, f);
    u = (u + 0x7FFFu + ((u >> 16) & 1u)) >> 16;
    return (unsigned short)u;
}
__device__ __forceinline__ float bf2f(unsigned short h) {
    unsigned int u = ((unsigned int)h) << 16;
    return __builtin_bit_cast(float, u);
}

__device__ __forceinline__ void gload_lds16(const void* g, void* l) {
    __builtin_amdgcn_global_load_lds(
        (const __attribute__((address_space(1))) void*)g,
        (__attribute__((address_space(3))) void*)l, 16, 0, 0);
}

// ---------------------------------------------------------------------------
// Weight conversion: fp32 -> bf16 hi/lo planes, with zero padding.
// ---------------------------------------------------------------------------
struct WTab {
    const float* src[10];
    long long dstOff[10];
    long long ps[10];
    int cum[10];
    int rows[10], cols[10], dcols[10];
    int n;
    int total;
};

__global__ void wconv_kernel(unsigned short* __restrict__ dst, WTab T)
{
    const int i = blockIdx.x * 256 + threadIdx.x;
    if (i >= T.total) return;
    int sI = 0;
    while (i >= T.cum[sI]) ++sI;
    const int e = i - (sI ? T.cum[sI - 1] : 0);
    const int dcols = T.dcols[sI];
    const int r = e / dcols;
    const int c = e - r * dcols;
    float v = 0.f;
    if (r < T.rows[sI] && c < T.cols[sI]) v = T.src[sI][(long long)r * T.cols[sI] + c];
    const unsigned short h = f2bf(v);
    const unsigned short l = f2bf(v - bf2f(h));
    dst[T.dstOff[sI] + e] = h;
    dst[T.dstOff[sI] + T.ps[sI] + e] = l;
}

// ---------------------------------------------------------------------------
// GEMM core (double-buffered): C[M,N] = A[M,K](fp32, split in-kernel)
//  * B[N,K]^T (bf16 hi/lo planes via global_load_lds DMA).
// Tile 64x128, BK=32, 4 waves. Prefetch tile t+1 issued right AFTER the
// barrier of tile t so the next barrier's vmcnt(0) drain lands after a full
// compute phase (latency hidden). One barrier per K-iteration.
// ---------------------------------------------------------------------------
__global__ __launch_bounds__(256, 3)
void gemm_direct(const float* __restrict__ Ag, const unsigned short* __restrict__ Bhl,
                 float* __restrict__ Cg, const float* __restrict__ biasg,
                 int M, int N, int K, int lda, int ldb, int ldc,
                 long long sA, long long sB, long long sC, long long sBias,
                 long long planeB, int flags)
{
    __shared__ __align__(16) unsigned short As[2][2][64][40];
    __shared__ __align__(16) unsigned short Bs[2][2][128][32];

    const int z = blockIdx.z;
    const float* A = Ag + (size_t)z * sA;
    const unsigned short* Bhi = Bhl + (size_t)z * sB;
    const unsigned short* Blo = Bhi + planeB;
    float* C = Cg + (size_t)z * sC;

    const int mBase = blockIdx.x * 64;
    const int nBase = blockIdx.y * 128;
    const int tid = threadIdx.x, lane = tid & 63, wave = tid >> 6;
    const int lm = lane & 15, lq = lane >> 4;
    const int wn = wave * 32;
    const int arow = tid >> 2, aq = tid & 3;
    const int brow = lane >> 2;
    const int bcol = (lane & 3) * 8;

    const int ktiles = (K + 31) >> 5;

    auto issueB = [&](int t, int buf) {
#pragma unroll
        for (int cc = 0; cc < 4; ++cc) {
            const int chunk = wave * 4 + cc;
            const int pl = chunk >> 3;
            const int r16 = chunk & 7;
            const unsigned short* bp = pl ? Blo : Bhi;
            const int n = nBase + r16 * 16 + brow;
            gload_lds16(bp + (size_t)n * ldb + t * 32 + bcol, &Bs[buf][pl][r16 * 16][0]);
        }
    };
    auto loadA = [&](int t, float* v) {
        const int col = t * 32 + aq * 8;
        const float* src = A + (size_t)(mBase + arow) * lda + col;
#pragma unroll
        for (int u = 0; u < 2; ++u) {
            float4 t4 = make_float4(0.f, 0.f, 0.f, 0.f);
            if (col + u * 4 < K) t4 = *(const float4*)(src + u * 4);
            v[u*4+0]=t4.x; v[u*4+1]=t4.y; v[u*4+2]=t4.z; v[u*4+3]=t4.w;
        }
    };
    auto writeA = [&](const float* v, int buf) {
        short8 ph, plv;
#pragma unroll
        for (int j = 0; j < 8; ++j) {
            unsigned short h = f2bf(v[j]);
            ph[j] = (short)h;
            plv[j] = (short)f2bf(v[j] - bf2f(h));
        }
        *(short8*)&As[buf][0][arow][aq * 8] = ph;
        *(short8*)&As[buf][1][arow][aq * 8] = plv;
    };

    float av[8];
    issueB(0, 0);
    loadA(0, av);
    writeA(av, 0);

    f32x4 acc[4][2] = {};
    for (int t = 0; t < ktiles; ++t) {
        const int buf = t & 1;
        __syncthreads();                       // drains B(t) DMA + A(t) writes
        const bool more = (t + 1) < ktiles;
        if (more) { issueB(t + 1, buf ^ 1); loadA(t + 1, av); }
        short8 ah[4], al[4], bh[2], bl[2];
#pragma unroll
        for (int i = 0; i < 4; ++i) {
            ah[i] = *(const short8*)&As[buf][0][16*i + lm][lq * 8];
            al[i] = *(const short8*)&As[buf][1][16*i + lm][lq * 8];
        }
#pragma unroll
        for (int j = 0; j < 2; ++j) {
            bh[j] = *(const short8*)&Bs[buf][0][wn + 16*j + lm][lq * 8];
            bl[j] = *(const short8*)&Bs[buf][1][wn + 16*j + lm][lq * 8];
        }
#pragma unroll
        for (int i = 0; i < 4; ++i)
#pragma unroll
            for (int j = 0; j < 2; ++j) {
                acc[i][j] = __builtin_amdgcn_mfma_f32_16x16x32_bf16(ah[i], bh[j], acc[i][j], 0, 0, 0);
                acc[i][j] = __builtin_amdgcn_mfma_f32_16x16x32_bf16(ah[i], bl[j], acc[i][j], 0, 0, 0);
                acc[i][j] = __builtin_amdgcn_mfma_f32_16x16x32_bf16(al[i], bh[j], acc[i][j], 0, 0, 0);
            }
        if (more) writeA(av, buf ^ 1);
    }

#pragma unroll
    for (int i = 0; i < 4; ++i)
#pragma unroll
        for (int j = 0; j < 2; ++j)
#pragma unroll
            for (int r = 0; r < 4; ++r) {
                const int m = mBase + i*16 + lq*4 + r;
                const int n = nBase + wn + j*16 + lm;
                float v = acc[i][j][r];
                if (flags & GF_BIAS)     v += biasg[(size_t)z * sBias + n];
                if (flags & GF_SOFTPLUS) v = (v > 20.f) ? v : log1pf(expf(v));
                C[(size_t)m * ldc + n] = v;
            }
}

// Split-K variant (double-buffered): grid.z = Z*S; partials Cp[(z*S+s)][M][ldP].
// kLen must be a multiple of 32.
__global__ __launch_bounds__(256, 3)
void gemm_splitk(const float* __restrict__ Ag, const unsigned short* __restrict__ Bhl,
                 float* __restrict__ Cp,
                 int M, int kLen, int S, int lda, int ldb, int ldP,
                 long long sA, long long sB, long long planeB)
{
    __shared__ __align__(16) unsigned short As[2][2][64][40];
    __shared__ __align__(16) unsigned short Bs[2][2][128][32];

    const int bz = blockIdx.z;
    const int s = bz % S, z = bz / S;
    const int kOff = s * kLen;
    const float* A = Ag + (size_t)z * sA;
    const unsigned short* Bhi = Bhl + (size_t)z * sB;
    const unsigned short* Blo = Bhi + planeB;

    const int mBase = blockIdx.x * 64;
    const int nBase = blockIdx.y * 128;
    const int tid = threadIdx.x, lane = tid & 63, wave = tid >> 6;
    const int lm = lane & 15, lq = lane >> 4;
    const int wn = wave * 32;
    const int arow = tid >> 2, aq = tid & 3;
    const int brow = lane >> 2;
    const int bcol = (lane & 3) * 8;

    const int ktiles = kLen >> 5;

    auto issueB = [&](int t, int buf) {
#pragma unroll
        for (int cc = 0; cc < 4; ++cc) {
            const int chunk = wave * 4 + cc;
            const int pl = chunk >> 3;
            const int r16 = chunk & 7;
            const unsigned short* bp = pl ? Blo : Bhi;
            const int n = nBase + r16 * 16 + brow;
            gload_lds16(bp + (size_t)n * ldb + kOff + t * 32 + bcol, &Bs[buf][pl][r16 * 16][0]);
        }
    };
    auto loadA = [&](int t, float* v) {
        const float* src = A + (size_t)(mBase + arow) * lda + kOff + t * 32 + aq * 8;
#pragma unroll
        for (int u = 0; u < 2; ++u) {
            const float4 t4 = *(const float4*)(src + u * 4);
            v[u*4+0]=t4.x; v[u*4+1]=t4.y; v[u*4+2]=t4.z; v[u*4+3]=t4.w;
        }
    };
    auto writeA = [&](const float* v, int buf) {
        short8 ph, plv;
#pragma unroll
        for (int j = 0; j < 8; ++j) {
            unsigned short h = f2bf(v[j]);
            ph[j] = (short)h;
            plv[j] = (short)f2bf(v[j] - bf2f(h));
        }
        *(short8*)&As[buf][0][arow][aq * 8] = ph;
        *(short8*)&As[buf][1][arow][aq * 8] = plv;
    };

    float av[8];
    issueB(0, 0);
    loadA(0, av);
    writeA(av, 0);

    f32x4 acc[4][2] = {};
    for (int t = 0; t < ktiles; ++t) {
        const int buf = t & 1;
        __syncthreads();
        const bool more = (t + 1) < ktiles;
        if (more) { issueB(t + 1, buf ^ 1); loadA(t + 1, av); }
        short8 ah[4], al[4], bh[2], bl[2];
#pragma unroll
        for (int i = 0; i < 4; ++i) {
            ah[i] = *(const short8*)&As[buf][0][16*i + lm][lq * 8];
            al[i] = *(const short8*)&As[buf][1][16*i + lm][lq * 8];
        }
#pragma unroll
        for (int j = 0; j < 2; ++j) {
            bh[j] = *(const short8*)&Bs[buf][0][wn + 16*j + lm][lq * 8];
            bl[j] = *(const short8*)&Bs[buf][1][wn + 16*j + lm][lq * 8];
        }
#pragma unroll
        for (int i = 0; i < 4; ++i)
#pragma unroll
            for (int j = 0; j < 2; ++j) {
                acc[i][j] = __builtin_amdgcn_mfma_f32_16x16x32_bf16(ah[i], bh[j], acc[i][j], 0, 0, 0);
                acc[i][j] = __builtin_amdgcn_mfma_f32_16x16x32_bf16(ah[i], bl[j], acc[i][j], 0, 0, 0);
                acc[i][j] = __builtin_amdgcn_mfma_f32_16x16x32_bf16(al[i], bh[j], acc[i][j], 0, 0, 0);
            }
        if (more) writeA(av, buf ^ 1);
    }

    float* Cb = Cp + (size_t)bz * M * ldP;
#pragma unroll
    for (int i = 0; i < 4; ++i)
#pragma unroll
        for (int j = 0; j < 2; ++j)
#pragma unroll
            for (int r = 0; r < 4; ++r) {
                const int m = mBase + i*16 + lq*4 + r;
                const int n = nBase + wn + j*16 + lm;
                Cb[(size_t)m * ldP + n] = acc[i][j][r];
            }
}

// Reduce partials + bias/residual, write fp32 out.
__global__ void epi_kernel(const float* __restrict__ Cp, float* __restrict__ outF,
                           const float* __restrict__ bias, const float* __restrict__ addT,
                           int Z, int S, int M, int N, int ldP, int ldOut,
                           long long sOutZ, long long sBiasZ, int ldAdd, int flags)
{
    const int n4 = N >> 2;
    const int idx = blockIdx.x * 256 + threadIdx.x;
    if (idx >= Z * M * n4) return;
    const int c4 = idx % n4;
    const int rem = idx / n4;
    const int m = rem % M;
    const int z = rem / M;
    const int n = c4 * 4;
    const float* base = Cp + ((size_t)z * S * M + m) * ldP + n;
    float4 v = *(const float4*)base;
    for (int s = 1; s < S; ++s) {
        const float4 u = *(const float4*)(base + (size_t)s * M * ldP);
        v.x += u.x; v.y += u.y; v.z += u.z; v.w += u.w;
    }
    if (flags & EPI_BIAS) {
        const float4 b4 = *(const float4*)(bias + (size_t)z * sBiasZ + n);
        v.x += b4.x; v.y += b4.y; v.z += b4.z; v.w += b4.w;
    }
    if (flags & EPI_ADDT) {
        const float4 a4 = *(const float4*)(addT + (size_t)m * ldAdd + n);
        v.x += a4.x; v.y += a4.y; v.z += a4.z; v.w += a4.w;
    }
    *(float4*)(outF + (size_t)z * sOutZ + (size_t)m * ldOut + n) = v;
}

// ---------------------------------------------------------------------------
// LayerNorm over last dim 768. One wave per row.
// ---------------------------------------------------------------------------
__global__ void ln_kernel(const float* __restrict__ in, float* __restrict__ out,
                          const float* __restrict__ g, const float* __restrict__ b, int rows)
{
    const int row = blockIdx.x * 4 + (threadIdx.x >> 6);
    const int lane = threadIdx.x & 63;
    if (row >= rows) return;
    const float* p = in + (size_t)row * DIMQ;
    float v[12], s = 0.f, s2 = 0.f;
#pragma unroll
    for (int j = 0; j < 12; ++j) {
        v[j] = p[j*64 + lane];
        s += v[j];
        s2 += v[j]*v[j];
    }
#pragma unroll
    for (int o = 32; o; o >>= 1) { s += __shfl_xor(s, o); s2 += __shfl_xor(s2, o); }
    const float mean = s * (1.f/768.f);
    const float var  = s2 * (1.f/768.f) - mean*mean;
    const float inv  = rsqrtf(var + 1e-5f);
    float* q = out + (size_t)row * DIMQ;
#pragma unroll
    for (int j = 0; j < 12; ++j) {
        const int c = j*64 + lane;
        q[c] = (v[j] - mean) * inv * g[c] + b[c];
    }
}

// ---------------------------------------------------------------------------
// Depthwise causal conv1d (DC=4) + silu.
// ---------------------------------------------------------------------------
__global__ void conv_kernel(const float* __restrict__ xz, float* __restrict__ xc,
                            const float* __restrict__ cw, const float* __restrict__ cb,
                            int Bn, int L, int instShift)
{
    const int idx = blockIdx.x * 256 + threadIdx.x;
    const int total = Bn * L * (DI/4);
    if (idx >= total) return;
    const int d4 = idx % (DI/4);
    const int t  = (idx / (DI/4)) % L;
    const int b  = idx / (L * (DI/4));
    const int inst = b >> instShift;
    const int d = d4 * 4;
    const float* base = xz + (size_t)(b * L) * 3072 + d;
    const float4 w0 = *(const float4*)(cw + (size_t)(inst*DI + d + 0) * 4);
    const float4 w1 = *(const float4*)(cw + (size_t)(inst*DI + d + 1) * 4);
    const float4 w2 = *(const float4*)(cw + (size_t)(inst*DI + d + 2) * 4);
    const float4 w3 = *(const float4*)(cw + (size_t)(inst*DI + d + 3) * 4);
    float4 acc = *(const float4*)(cb + (size_t)inst*DI + d);
    float4 xv[4];
#pragma unroll
    for (int j = 0; j < 4; ++j) {
        const int tt = t - 3 + j;
        xv[j] = (tt >= 0) ? *(const float4*)(base + (size_t)tt * 3072) : make_float4(0,0,0,0);
    }
    acc.x += xv[0].x*w0.x + xv[1].x*w0.y + xv[2].x*w0.z + xv[3].x*w0.w;
    acc.y += xv[0].y*w1.x + xv[1].y*w1.y + xv[2].y*w1.z + xv[3].y*w1.w;
    acc.z += xv[0].z*w2.x + xv[1].z*w2.y + xv[2].z*w2.z + xv[3].z*w2.w;
    acc.w += xv[0].w*w3.x + xv[1].w*w3.y + xv[2].w*w3.z + xv[3].w*w3.w;
    float4 o;
    o.x = acc.x / (1.f + expf(-acc.x));
    o.y = acc.y / (1.f + expf(-acc.y));
    o.z = acc.z / (1.f + expf(-acc.z));
    o.w = acc.w / (1.f + expf(-acc.w));
    *(float4*)(xc + (size_t)(b * L + t) * DI + d) = o;
}

// ---------------------------------------------------------------------------
// Chunked selective scan (3 passes).
// ---------------------------------------------------------------------------
__global__ __launch_bounds__(256)
void scan_p1(const float* __restrict__ dt, const float* __restrict__ dbl,
             const float* __restrict__ xc, const float* __restrict__ A_log,
             float* __restrict__ hend, float* __restrict__ sumdt,
             int L, int CL, int Bn, int instShift)
{
    const int d = blockIdx.x * 256 + threadIdx.x;
    const int b = blockIdx.y;
    const int c = blockIdx.z;
    const int inst = b >> instShift;
    const float* ap = A_log + ((size_t)inst * DI + d) * DS;
    float A2[16];
#pragma unroll
    for (int s = 0; s < 16; ++s) A2[s] = -expf(ap[s]) * LOG2E;
    float h[16] = {};
    float sd = 0.f;
    const int t0 = c * CL;
    const size_t rowbase = (size_t)b * L;
    for (int t = t0; t < t0 + CL; ++t) {
        const size_t row = rowbase + t;
        const float dtv = dt[row * DI + d];
        const float xcv = xc[row * DI + d];
        float Bv[16];
        *(float4*)(Bv + 0)  = *(const float4*)(dbl + row * 80 + 48);
        *(float4*)(Bv + 4)  = *(const float4*)(dbl + row * 80 + 52);
        *(float4*)(Bv + 8)  = *(const float4*)(dbl + row * 80 + 56);
        *(float4*)(Bv + 12) = *(const float4*)(dbl + row * 80 + 60);
        sd += dtv;
        const float bx = dtv * xcv;
#pragma unroll
        for (int s = 0; s < 16; ++s)
            h[s] = exp2f(dtv * A2[s]) * h[s] + bx * Bv[s];
    }
    float* hp = hend + (((size_t)c * Bn + b) * DI + d) * DS;
#pragma unroll
    for (int s = 0; s < 16; s += 4)
        *(float4*)(hp + s) = make_float4(h[s], h[s+1], h[s+2], h[s+3]);
    sumdt[((size_t)c * Bn + b) * DI + d] = sd;
}

__global__ void scan_p2(const float* __restrict__ hend, const float* __restrict__ sumdt,
                        const float* __restrict__ A_log, float* __restrict__ hstart,
                        int NC, int Bn, int instShift)
{
    const int gid = blockIdx.x * 256 + threadIdx.x;
    const int s = gid & 15;
    const int rem = gid >> 4;
    const int d = rem % DI;
    const int b = rem / DI;
    const int inst = b >> instShift;
    const float A2 = -expf(A_log[((size_t)inst * DI + d) * DS + s]) * LOG2E;
    float carry = 0.f;
    for (int c = 0; c < NC; ++c) {
        const size_t off = (((size_t)c * Bn + b) * DI + d) * DS + s;
        hstart[off] = carry;
        carry = exp2f(A2 * sumdt[((size_t)c * Bn + b) * DI + d]) * carry + hend[off];
    }
}

__global__ __launch_bounds__(256)
void scan_p3(const float* __restrict__ dt, const float* __restrict__ dbl,
             const float* __restrict__ xc, const float* __restrict__ xz,
             const float* __restrict__ A_log, const float* __restrict__ Dp,
             const float* __restrict__ hstart, float* __restrict__ y,
             int L, int CL, int Bn, int instShift)
{
    const int d = blockIdx.x * 256 + threadIdx.x;
    const int b = blockIdx.y;
    const int c = blockIdx.z;
    const int inst = b >> instShift;
    const float* ap = A_log + ((size_t)inst * DI + d) * DS;
    float A2[16];
#pragma unroll
    for (int s = 0; s < 16; ++s) A2[s] = -expf(ap[s]) * LOG2E;
    const float Dd = Dp[(size_t)inst * DI + d];
    float h[16];
    const float* hp = hstart + (((size_t)c * Bn + b) * DI + d) * DS;
#pragma unroll
    for (int s = 0; s < 16; s += 4) {
        const float4 t4 = *(const float4*)(hp + s);
        h[s] = t4.x; h[s+1] = t4.y; h[s+2] = t4.z; h[s+3] = t4.w;
    }
    const int t0 = c * CL;
    const size_t rowbase = (size_t)b * L;
    for (int t = t0; t < t0 + CL; ++t) {
        const size_t row = rowbase + t;
        const float dtv = dt[row * DI + d];
        const float xcv = xc[row * DI + d];
        const float zv  = xz[row * 3072 + DI + d];
        float Bv[16], Cv[16];
        *(float4*)(Bv + 0)  = *(const float4*)(dbl + row * 80 + 48);
        *(float4*)(Bv + 4)  = *(const float4*)(dbl + row * 80 + 52);
        *(float4*)(Bv + 8)  = *(const float4*)(dbl + row * 80 + 56);
        *(float4*)(Bv + 12) = *(const float4*)(dbl + row * 80 + 60);
        *(float4*)(Cv + 0)  = *(const float4*)(dbl + row * 80 + 64);
        *(float4*)(Cv + 4)  = *(const float4*)(dbl + row * 80 + 68);
        *(float4*)(Cv + 8)  = *(const float4*)(dbl + row * 80 + 72);
        *(float4*)(Cv + 12) = *(const float4*)(dbl + row * 80 + 76);
        const float bx = dtv * xcv;
#pragma unroll
        for (int s = 0; s < 16; ++s)
            h[s] = exp2f(dtv * A2[s]) * h[s] + bx * Bv[s];
        float p0 = 0.f, p1 = 0.f, p2 = 0.f, p3 = 0.f;
#pragma unroll
        for (int s = 0; s < 4; ++s) {
            p0 += h[s]      * Cv[s];
            p1 += h[s + 4]  * Cv[s + 4];
            p2 += h[s + 8]  * Cv[s + 8];
            p3 += h[s + 12] * Cv[s + 12];
        }
        const float p = (p0 + p1) + (p2 + p3);
        y[row * DI + d] = (p + Dd * xcv) * (zv / (1.f + expf(-zv)));
    }
}

// ---------------------------------------------------------------------------
// Local-window cross attention (2-3 keys/query).
// ---------------------------------------------------------------------------
__global__ void attn_kernel(const float* __restrict__ q, const float* __restrict__ kv,
                            float* __restrict__ o)
{
    const int bi = blockIdx.x;
    const int b = bi / NQ, i = bi % NQ;
    const int tid = threadIdx.x;
    const int h = tid >> 2, r = tid & 3;
    int start, len;
    if (i < 256) { start = 3*i; len = 3; } else { start = 2*i + 256; len = 2; }
    const float* qp = q + (size_t)bi * DIMQ + h*48 + r*12;
    float qv[12];
#pragma unroll
    for (int u = 0; u < 12; ++u) qv[u] = qp[u];
    float s[3] = {-1e30f, -1e30f, -1e30f};
    for (int j = 0; j < len; ++j) {
        const float* kp = kv + (size_t)(b*LSEQ + start + j) * 1536 + h*48 + r*12;
        float p = 0.f;
#pragma unroll
        for (int u = 0; u < 12; ++u) p += qv[u] * kp[u];
        p += __shfl_xor(p, 1);
        p += __shfl_xor(p, 2);
        s[j] = p * 0.14433756729740644f;
    }
    const float mx = fmaxf(s[0], fmaxf(s[1], s[2]));
    float e[3];
    e[0] = expf(s[0]-mx); e[1] = expf(s[1]-mx); e[2] = expf(s[2]-mx);
    const float inv = 1.f / (e[0] + e[1] + e[2]);
    float ov[12] = {};
    for (int j = 0; j < len; ++j) {
        const float w = e[j] * inv;
        const float* vp = kv + (size_t)(b*LSEQ + start + j) * 1536 + 768 + h*48 + r*12;
#pragma unroll
        for (int u = 0; u < 12; ++u) ov[u] += w * vp[u];
    }
    float* op = o + (size_t)bi * DIMQ + h*48 + r*12;
#pragma unroll
    for (int u = 0; u < 12; ++u) op[u] = ov[u];
}

// ---------------------------------------------------------------------------
// small utility kernels
// ---------------------------------------------------------------------------
__global__ void flip_kernel(float* __restrict__ X2)
{
    const int idx = blockIdx.x * 256 + threadIdx.x;
    if (idx >= 2*1024*192) return;
    const int d4 = idx % 192;
    const int t  = (idx / 192) % 1024;
    const int b  = idx / (192 * 1024);
    const size_t dst = ((size_t)((2+b)*1024 + t)) * DIMQ + d4*4;
    const size_t src = ((size_t)(b*1024 + (1023 - t))) * DIMQ + d4*4;
    *(float4*)(X2 + dst) = *(const float4*)(X2 + src);
}

__global__ void combine_kernel(const float* __restrict__ oe, const float* __restrict__ feats,
                               float* __restrict__ c)
{
    const int idx = blockIdx.x * 256 + threadIdx.x;
    if (idx >= 2*1024*192) return;
    const int d4 = idx % 192;
    const int t  = (idx / 192) % 1024;
    const int b  = idx / (192 * 1024);
    const size_t fw = ((size_t)(b*1024 + t)) * DIMQ + d4*4;
    const size_t bw = ((size_t)((2+b)*1024 + (1023 - t))) * DIMQ + d4*4;
    const float4 a = *(const float4*)(oe + fw);
    const float4 bb = *(const float4*)(oe + bw);
    const float4 f = *(const float4*)(feats + fw);
    float4 o;
    o.x = a.x + bb.x + f.x; o.y = a.y + bb.y + f.y;
    o.z = a.z + bb.z + f.z; o.w = a.w + bb.w + f.w;
    *(float4*)(c + fw) = o;
}

__global__ void qinit_kernel(float* __restrict__ x, const float* __restrict__ queries)
{
    const int idx = blockIdx.x * 256 + threadIdx.x;
    if (idx >= 2*NQ*192) return;
    const int d4 = idx % 192;
    const int i  = (idx / 192) % NQ;
    *(float4*)(x + (size_t)idx * 4) = *(const float4*)(queries + ((size_t)i * DIMQ + d4*4));
}

// ---------------------------------------------------------------------------
extern "C" void kernel_launch(void* const* d_in, const int* in_sizes, int n_in,
                              void* d_out, int out_size, void* d_ws, size_t ws_size,
                              hipStream_t stream) {
    const float* img_emb  = (const float*)d_in[0];
    const float* queries  = (const float*)d_in[1];
    const float* vis_w    = (const float*)d_in[2];
    const float* vis_b    = (const float*)d_in[3];
    const float* lnv_g    = (const float*)d_in[4];
    const float* lnv_b    = (const float*)d_in[5];
    const float* m_in_w   = (const float*)d_in[6];
    const float* m_conv_w = (const float*)d_in[7];
    const float* m_conv_b = (const float*)d_in[8];
    const float* m_xp_w   = (const float*)d_in[9];
    const float* m_dt_w   = (const float*)d_in[10];
    const float* m_dt_b   = (const float*)d_in[11];
    const float* m_A_log  = (const float*)d_in[12];
    const float* m_D      = (const float*)d_in[13];
    const float* m_out_w  = (const float*)d_in[14];
    const float* sn_g     = (const float*)d_in[15];
    const float* sn_b     = (const float*)d_in[16];
    const float* a_in_w   = (const float*)d_in[17];
    const float* a_in_b   = (const float*)d_in[18];
    const float* a_out_w  = (const float*)d_in[19];
    const float* a_out_b  = (const float*)d_in[20];
    const float* cr_w     = (const float*)d_in[21];
    const float* cr_b     = (const float*)d_in[22];
    float* out = (float*)d_out;

    float* ws = (float*)d_ws;
    float* X2   = ws; ws += (size_t)4096*768;
    float* xzb  = ws; ws += (size_t)4096*3072;
    float* xcb  = ws; ws += (size_t)4096*1536;
    float* dblb = ws; ws += (size_t)4096*80;
    float* dtb  = ws; ws += (size_t)4096*1536;
    float* yb   = ws; ws += (size_t)4096*1536;
    float* oe   = ws; ws += (size_t)4096*768;
    float* cbuf = ws; ws += (size_t)2048*768;
    float* xbuf = ws; ws += (size_t)768*768;
    float* xn   = ws; ws += (size_t)768*768;
    float* x1s  = ws; ws += (size_t)768*1536;
    float* qb   = ws; ws += (size_t)768*768;
    float* ob   = ws; ws += (size_t)768*768;
    float* Cp   = ws; ws += (size_t)2359296;
    unsigned short* wenc = (unsigned short*)ws; ws += (size_t)16908288/2;
    unsigned short* wlay = (unsigned short*)ws; ws += (size_t)14745600/2;

    const long long P_VIS = 768LL*1024;
    const long long P_IN  = 3072LL*768;
    const long long P_XP  = 128LL*1536;
    const long long P_DT  = 1536LL*64;
    const long long P_OUT = 768LL*1536;
    const long long P_AIN = 2304LL*768;
    const long long P_AOUT= 768LL*768;
    const long long P_CR  = 768LL*1536;
    const long long off_vis   = 0;
    const long long off_encIn = 2*P_VIS;
    const long long off_encXp = off_encIn + 4*P_IN;
    const long long off_encDt = off_encXp + 4*P_XP;
    const long long off_encOut= off_encDt + 4*P_DT;
    const long long off_in  = 0;
    const long long off_xp  = 2*P_IN;
    const long long off_dt  = off_xp + 2*P_XP;
    const long long off_out = off_dt + 2*P_DT;
    const long long off_aIn = off_out + 2*P_OUT;
    const long long off_aOut= off_aIn + 2*P_AIN;
    const long long off_cr  = off_aOut + 2*P_AOUT;

    auto addSeg = [](WTab& T, const float* src, int rows, int cols, int drows, int dcols,
                     long long dstOff) {
        const int k = T.n;
        T.src[k] = src; T.rows[k] = rows; T.cols[k] = cols; T.dcols[k] = dcols;
        T.ps[k] = (long long)drows * dcols;
        T.dstOff[k] = dstOff;
        T.total += drows * dcols;
        T.cum[k] = T.total;
        T.n = k + 1;
    };

    auto GD = [&](const float* A, const unsigned short* Bhl, long long planeB,
                  float* C, const float* bias,
                  int M, int N, int K, int lda, int ldb, int ldc,
                  long long sA, long long sB, long long sC, long long sBias,
                  int Z, int flags) {
        dim3 grid(M/64, N/128, Z);
        gemm_direct<<<grid, 256, 0, stream>>>(A, Bhl, C, bias, M, N, K, lda, ldb, ldc,
                                              sA, sB, sC, sBias, planeB, flags);
    };
    auto GS = [&](const float* A, const unsigned short* Bhl, long long planeB,
                  int M, int Ntile, int kLen, int S, int lda, int ldb, int ldP,
                  long long sA, long long sB, int Z) {
        dim3 grid(M/64, Ntile/128, Z*S);
        gemm_splitk<<<grid, 256, 0, stream>>>(A, Bhl, Cp, M, kLen, S, lda, ldb, ldP,
                                              sA, sB, planeB);
    };
    auto EPI = [&](float* outF, const float* bias, const float* addT,
                   int Z, int S, int M, int N, int ldP, int ldOut,
                   long long sOutZ, long long sBiasZ, int ldAdd, int flags) {
        const int total = Z * M * (N/4);
        epi_kernel<<<(total+255)/256, 256, 0, stream>>>(Cp, outF, bias, addT, Z, S, M, N,
                                                        ldP, ldOut, sOutZ, sBiasZ, ldAdd, flags);
    };

    // ==== encoder weight conversion ====
    {
        WTab T = {}; T.n = 0; T.total = 0;
        addSeg(T, vis_w, 768, 1024, 768, 1024, off_vis);
        addSeg(T, m_in_w,               3072, 768, 3072, 768, off_encIn);
        addSeg(T, m_in_w + 3072*768,    3072, 768, 3072, 768, off_encIn + 2*P_IN);
        addSeg(T, m_xp_w,               80, 1536, 128, 1536, off_encXp);
        addSeg(T, m_xp_w + 80*1536,     80, 1536, 128, 1536, off_encXp + 2*P_XP);
        addSeg(T, m_dt_w,               1536, 48, 1536, 64, off_encDt);
        addSeg(T, m_dt_w + 1536*48,     1536, 48, 1536, 64, off_encDt + 2*P_DT);
        addSeg(T, m_out_w,              768, 1536, 768, 1536, off_encOut);
        addSeg(T, m_out_w + 768*1536,   768, 1536, 768, 1536, off_encOut + 2*P_OUT);
        wconv_kernel<<<(T.total+255)/256, 256, 0, stream>>>(wenc, T);
    }

    // ==== vision proj + LN + stacked feats ====
    GD(img_emb, wenc + off_vis, P_VIS, oe, vis_b,
       2048, 768, 1024, 1024, 1024, 768, 0,0,0,0, 1, GF_BIAS);
    ln_kernel<<<512, 256, 0, stream>>>(oe, X2, lnv_g, lnv_b, 2048);
    flip_kernel<<<(2*1024*192 + 255)/256, 256, 0, stream>>>(X2);
    qinit_kernel<<<(2*NQ*192 + 255)/256, 256, 0, stream>>>(xbuf, queries);

    // ==== encoder mambas (fwd + bwd via Z=2) ====
    GD(X2, wenc + off_encIn, P_IN, xzb, nullptr,
       2048, 3072, 768, 768, 768, 3072, 2048LL*768, 2*P_IN, 2048LL*3072, 0, 2, 0);
    conv_kernel<<<(4*1024*384 + 255)/256, 256, 0, stream>>>(xzb, xcb, m_conv_w, m_conv_b, 4, 1024, 1);
    GS(xcb, wenc + off_encXp, P_XP, 2048, 128, 384, 4, 1536, 1536, 128,
       2048LL*1536, 2*P_XP, 2);
    EPI(dblb, nullptr, nullptr, 2, 4, 2048, 80, 128, 80, 2048LL*80, 0, 0, 0);
    GD(dblb, wenc + off_encDt, P_DT, dtb, m_dt_b,
       2048, 1536, 48, 80, 64, 1536, 2048LL*80, 2*P_DT, 2048LL*1536, 1536, 2,
       GF_BIAS | GF_SOFTPLUS);
    {
        const int NC = 8, CL = 128;
        float* hend   = oe;
        float* hstart = oe + (size_t)NC*4*DI*DS;
        float* sumdt  = oe + (size_t)2*NC*4*DI*DS;
        scan_p1<<<dim3(6, 4, NC), 256, 0, stream>>>(dtb, dblb, xcb, m_A_log, hend, sumdt, 1024, CL, 4, 1);
        scan_p2<<<(4*DI*DS)/256, 256, 0, stream>>>(hend, sumdt, m_A_log, hstart, NC, 4, 1);
        scan_p3<<<dim3(6, 4, NC), 256, 0, stream>>>(dtb, dblb, xcb, xzb, m_A_log, m_D, hstart, yb, 1024, CL, 4, 1);
    }
    GD(yb, wenc + off_encOut, P_OUT, oe, nullptr,
       2048, 768, 1536, 1536, 1536, 768, 2048LL*1536, 2*P_OUT, 2048LL*768, 0, 2, 0);
    combine_kernel<<<(2*1024*192 + 255)/256, 256, 0, stream>>>(oe, X2, cbuf);

    // ==== 12 blocks ====
    for (int l = 0; l < NBK; ++l) {
        const int li = l + 2;
        {
            WTab T = {}; T.n = 0; T.total = 0;
            addSeg(T, m_in_w + (size_t)li*3072*768, 3072, 768, 3072, 768, off_in);
            addSeg(T, m_xp_w + (size_t)li*80*1536,  80, 1536, 128, 1536, off_xp);
            addSeg(T, m_dt_w + (size_t)li*1536*48,  1536, 48, 1536, 64, off_dt);
            addSeg(T, m_out_w + (size_t)li*768*1536, 768, 1536, 768, 1536, off_out);
            addSeg(T, a_in_w + (size_t)l*2304*768,  2304, 768, 2304, 768, off_aIn);
            addSeg(T, a_out_w + (size_t)l*768*768,  768, 768, 768, 768, off_aOut);
            addSeg(T, cr_w + (size_t)l*768*1536,    768, 1536, 768, 1536, off_cr);
            wconv_kernel<<<(T.total+255)/256, 256, 0, stream>>>(wlay, T);
        }
        ln_kernel<<<192, 256, 0, stream>>>(xbuf, xn, sn_g + (size_t)l*768, sn_b + (size_t)l*768, 768);
        GD(xn, wlay + off_in, P_IN, xzb, nullptr,
           768, 3072, 768, 768, 768, 3072, 0,0,0,0, 1, 0);
        conv_kernel<<<(2*NQ*384 + 255)/256, 256, 0, stream>>>(
            xzb, xcb, m_conv_w + (size_t)li*DI*4, m_conv_b + (size_t)li*DI, 2, NQ, 8);
        GS(xcb, wlay + off_xp, P_XP, 768, 128, 96, 16, 1536, 1536, 128, 0, 0, 1);
        EPI(dblb, nullptr, nullptr, 1, 16, 768, 80, 128, 80, 0, 0, 0, 0);
        GD(dblb, wlay + off_dt, P_DT, dtb, m_dt_b + (size_t)li*1536,
           768, 1536, 48, 80, 64, 1536, 0,0,0,0, 1, GF_BIAS | GF_SOFTPLUS);
        {
            const int NC = 12, CL = 32;
            const float* Ap = m_A_log + (size_t)li*DI*DS;
            float* hend   = oe;
            float* hstart = oe + (size_t)NC*2*DI*DS;
            float* sumdt  = oe + (size_t)2*NC*2*DI*DS;
            scan_p1<<<dim3(6, 2, NC), 256, 0, stream>>>(dtb, dblb, xcb, Ap, hend, sumdt, NQ, CL, 2, 8);
            scan_p2<<<(2*DI*DS)/256, 256, 0, stream>>>(hend, sumdt, Ap, hstart, NC, 2, 8);
            scan_p3<<<dim3(6, 2, NC), 256, 0, stream>>>(dtb, dblb, xcb, xzb, Ap, m_D + (size_t)li*DI,
                                                        hstart, yb, NQ, CL, 2, 8);
        }
        GS(yb, wlay + off_out, P_OUT, 768, 768, 384, 4, 1536, 1536, 768, 0, 0, 1);
        EPI(x1s, nullptr, xn, 1, 4, 768, 768, 768, 1536, 0, 0, 768, EPI_ADDT);
        GS(x1s, wlay + off_aIn, P_AIN, 768, 768, 192, 4, 1536, 768, 768, 0, 0, 1);
        EPI(qb, a_in_b + (size_t)l*2304, nullptr, 1, 4, 768, 768, 768, 768, 0, 0, 0, EPI_BIAS);
        GD(cbuf, wlay + off_aIn + 768LL*768, P_AIN, oe, a_in_b + (size_t)l*2304 + 768,
           2048, 1536, 768, 768, 768, 1536, 0,0,0,0, 1, GF_BIAS);
        attn_kernel<<<2*NQ, 64, 0, stream>>>(qb, oe, ob);
        GS(ob, wlay + off_aOut, P_AOUT, 768, 768, 192, 4, 768, 768, 768, 0, 0, 1);
        EPI(x1s + 768, a_out_b + (size_t)l*768, nullptr, 1, 4, 768, 768, 768, 1536, 0, 0, 0, EPI_BIAS);
        float* dst = (l == NBK - 1) ? out : xbuf;
        GS(x1s, wlay + off_cr, P_CR, 768, 768, 384, 4, 1536, 1536, 768, 0, 0, 1);
        EPI(dst, cr_b + (size_t)l*768, nullptr, 1, 4, 768, 768, 768, 768, 0, 0, 0, EPI_BIAS);
    }
}